// Round 2
// baseline (2666.004 us; speedup 1.0000x reference)
//
#include <hip/hip_runtime.h>
#include <hip/hip_bf16.h>

#define AS1 __attribute__((address_space(1)))
#define AS3 __attribute__((address_space(3)))

typedef __bf16 bf16x8 __attribute__((ext_vector_type(8)));
typedef float f32x4 __attribute__((ext_vector_type(4)));

static constexpr int C_DIM = 1024;
static constexpr int H_DIM = 4096;
static constexpr int NTOK  = 8192;   // 4*2048
static constexpr int NR    = 7;      // routed experts
static constexpr int MAXG  = 17408;  // gathered-row capacity (16384 + 7*128 pad)
static constexpr size_t WSZ = (size_t)C_DIM * H_DIM;  // elems per expert weight

static __device__ __forceinline__ unsigned short f2bf(float f) {
  __hip_bfloat16 h = __float2bfloat16(f);
  return *reinterpret_cast<unsigned short*>(&h);
}

static __device__ __forceinline__ void gload16(const void* g, void* lds) {
  __builtin_amdgcn_global_load_lds((const AS1 void*)g, (AS3 void*)lds, 16, 0, 0);
}

// ---------------- cast x (fp32 -> bf16) ----------------
__global__ __launch_bounds__(256) void cast_x_kernel(const float* __restrict__ x,
                                                     unsigned short* __restrict__ xb) {
  size_t i = ((size_t)blockIdx.x * blockDim.x + threadIdx.x) * 4;
  float4 v = *(const float4*)(x + i);
  ushort4 o;
  o.x = f2bf(v.x); o.y = f2bf(v.y); o.z = f2bf(v.z); o.w = f2bf(v.w);
  *(ushort4*)(xb + i) = o;
}

// ---------------- init: zero idx / cnt / cursor ----------------
__global__ __launch_bounds__(256) void init_kernel(int* __restrict__ idx, int* __restrict__ cnt,
                                                   int* __restrict__ cursor) {
  int i = blockIdx.x * 256 + threadIdx.x;
  if (i < MAXG) idx[i] = 0;
  if (blockIdx.x == 0 && threadIdx.x < 8) { cnt[threadIdx.x] = 0; cursor[threadIdx.x] = 0; }
}

// ---------------- routing: one wave per token; writes cw + counts ----------------
__global__ __launch_bounds__(256) void routing_kernel(const float* __restrict__ x,
                                                      const float* __restrict__ gw,
                                                      const float* __restrict__ bias,
                                                      float* __restrict__ cw,
                                                      int* __restrict__ cnt) {
  int wid = (int)((blockIdx.x * (size_t)blockDim.x + threadIdx.x) >> 6);
  int lane = threadIdx.x & 63;
  if (wid >= NTOK) return;
  const float* xt = x + (size_t)wid * C_DIM;
  float p[NR] = {0.f, 0.f, 0.f, 0.f, 0.f, 0.f, 0.f};
  for (int i = lane; i < C_DIM; i += 64) {
    float xv = xt[i];
#pragma unroll
    for (int e = 0; e < NR; ++e) p[e] += xv * gw[e * C_DIM + i];
  }
#pragma unroll
  for (int e = 0; e < NR; ++e) {
#pragma unroll
    for (int off = 32; off; off >>= 1) p[e] += __shfl_down(p[e], off);
  }
  if (lane == 0) {
    float m = p[0];
#pragma unroll
    for (int e = 1; e < NR; ++e) m = fmaxf(m, p[e]);
    float pr[NR], s = 0.f;
#pragma unroll
    for (int e = 0; e < NR; ++e) { pr[e] = __expf(p[e] - m); s += pr[e]; }
    float inv = 1.0f / s;
#pragma unroll
    for (int e = 0; e < NR; ++e) pr[e] *= inv;
    float sel[NR];
#pragma unroll
    for (int e = 0; e < NR; ++e) sel[e] = p[e] + bias[e];
    int i1 = 0;
#pragma unroll
    for (int e = 1; e < NR; ++e) if (sel[e] > sel[i1]) i1 = e;
    int i2 = -1;
#pragma unroll
    for (int e = 0; e < NR; ++e) {
      if (e == i1) continue;
      if (i2 < 0 || sel[e] > sel[i2]) i2 = e;
    }
    float c[NR] = {0.f, 0.f, 0.f, 0.f, 0.f, 0.f, 0.f};
    c[i1] = pr[i1];
    c[i2] += pr[i2];
#pragma unroll
    for (int e = 0; e < NR; ++e) cw[(size_t)wid * NR + e] = c[e];
    atomicAdd(&cnt[i1], 1);
    atomicAdd(&cnt[i2], 1);
  }
}

// ---------------- scan: tile-aligned exclusive prefix of counts ----------------
__global__ void scan_kernel(const int* __restrict__ cnt, int* __restrict__ offs) {
  int o = 0;
  for (int e = 0; e < NR; ++e) { offs[e] = o; o += (cnt[e] + 127) & ~127; }
}

// ---------------- place: fill gathered index lists ----------------
__global__ __launch_bounds__(256) void place_kernel(const float* __restrict__ cw,
                                                    const int* __restrict__ offs,
                                                    int* __restrict__ cursor,
                                                    int* __restrict__ idx) {
  int t = blockIdx.x * 256 + threadIdx.x;
  if (t >= NTOK) return;
#pragma unroll
  for (int e = 0; e < NR; ++e) {
    if (cw[(size_t)t * NR + e] > 0.f) {
      int p = atomicAdd(&cursor[e], 1);
      idx[offs[e] + p] = t;
    }
  }
}

// ---------------- transpose + cast all 8 experts: fp32 [R][S] -> bf16 [S][R] ----------------
__global__ void transpose_cast_all(const float* __restrict__ shared_w,
                                   const float* __restrict__ routed_w,
                                   unsigned short* __restrict__ out, int R, int S) {
  int e = blockIdx.z;
  const float* in = (e == 0) ? shared_w : routed_w + (size_t)(e - 1) * R * S;
  unsigned short* o = out + (size_t)e * R * S;
  __shared__ float t[32][33];
  int bx = blockIdx.x * 32;  // S
  int by = blockIdx.y * 32;  // R
  int tx = threadIdx.x, ty = threadIdx.y;  // (32, 8)
#pragma unroll
  for (int i = 0; i < 32; i += 8)
    t[ty + i][tx] = in[(size_t)(by + ty + i) * S + bx + tx];
  __syncthreads();
#pragma unroll
  for (int i = 0; i < 32; i += 8)
    o[(size_t)(bx + ty + i) * R + by + tx] = f2bf(t[tx][ty + i]);
}

// ---------------- fc GEMM: A rows (gathered) x wfcT -> gelu -> Y (bf16) ----------------
template <bool GATHER>
__global__ __launch_bounds__(256) void gemm_fc(const unsigned short* __restrict__ A,
                                               const unsigned short* __restrict__ BtAll,
                                               unsigned short* __restrict__ Y,
                                               const int* __restrict__ idx,
                                               const int* __restrict__ offs,
                                               const int* __restrict__ cnt) {
  __shared__ __align__(16) unsigned short As[4 * 128 * 8];
  __shared__ __align__(16) unsigned short Bs[4 * 128 * 8];
  const int tid = threadIdx.x;
  const int wave = tid >> 6, lane = tid & 63;

  // bijective XCD swizzle over the xy tile plane (grid xy divisible by 8)
  const int f = blockIdx.y * gridDim.x + blockIdx.x;
  const int cpx = (gridDim.x * gridDim.y) >> 3;
  const int swz = (f & 7) * cpx + (f >> 3);
  const int bx = swz % gridDim.x, by = swz / gridDim.x;

  const int m0 = by * 128, n0 = bx * 128;
  const int e = GATHER ? blockIdx.z : 0;
  const int cnt_e = GATHER ? cnt[e] : NTOK;
  if (GATHER && m0 >= cnt_e) return;
  const int base = GATHER ? offs[e] : 0;
  const unsigned short* Bt = BtAll + (GATHER ? (size_t)(e + 1) * WSZ : 0);

  // loop-invariant staging assignment: 2 chunks/thread, fixed (kg,row)
  const int q0 = wave * 128 + lane, q1 = q0 + 64;
  const int kg0 = q0 >> 7, r0 = q0 & 127;
  const int kg1 = q1 >> 7, r1 = q1 & 127;
  const size_t rowA0 = GATHER ? (size_t)idx[base + m0 + r0] : (size_t)(m0 + r0);
  const size_t rowA1 = GATHER ? (size_t)idx[base + m0 + r1] : (size_t)(m0 + r1);
  const unsigned short* gA0 = A + rowA0 * C_DIM + kg0 * 8;
  const unsigned short* gA1 = A + rowA1 * C_DIM + kg1 * 8;
  const unsigned short* gB0 = Bt + (size_t)(n0 + r0) * C_DIM + kg0 * 8;
  const unsigned short* gB1 = Bt + (size_t)(n0 + r1) * C_DIM + kg1 * 8;
  unsigned short* lA0 = &As[(wave * 2 + 0) * 512];
  unsigned short* lA1 = &As[(wave * 2 + 1) * 512];
  unsigned short* lB0 = &Bs[(wave * 2 + 0) * 512];
  unsigned short* lB1 = &Bs[(wave * 2 + 1) * 512];

  const int wr = wave >> 1, wc = wave & 1;
  const int fr = lane & 15, fq = lane >> 4;
  f32x4 acc[4][4] = {};

  for (int k0 = 0; k0 < C_DIM; k0 += 32) {
    gload16(gA0 + k0, lA0);
    gload16(gA1 + k0, lA1);
    gload16(gB0 + k0, lB0);
    gload16(gB1 + k0, lB1);
    __syncthreads();
    bf16x8 af[4], bfr[4];
#pragma unroll
    for (int m = 0; m < 4; ++m)
      af[m] = *(const bf16x8*)&As[fq * 1024 + (wr * 64 + m * 16 + fr) * 8];
#pragma unroll
    for (int n = 0; n < 4; ++n)
      bfr[n] = *(const bf16x8*)&Bs[fq * 1024 + (wc * 64 + n * 16 + fr) * 8];
#pragma unroll
    for (int m = 0; m < 4; ++m)
#pragma unroll
      for (int n = 0; n < 4; ++n)
        acc[m][n] = __builtin_amdgcn_mfma_f32_16x16x32_bf16(af[m], bfr[n], acc[m][n], 0, 0, 0);
    __syncthreads();
  }

#pragma unroll
  for (int m = 0; m < 4; ++m)
#pragma unroll
    for (int n = 0; n < 4; ++n)
#pragma unroll
      for (int j = 0; j < 4; ++j) {
        const int row = m0 + wr * 64 + m * 16 + fq * 4 + j;
        const int col = n0 + wc * 64 + n * 16 + fr;
        const float v = acc[m][n][j];
        const float g = 0.5f * v * (1.0f + erff(v * 0.70710678118654752f));
        Y[(size_t)(base + row) * H_DIM + col] = f2bf(g);
      }
}

// ---------------- proj GEMM: Y x wprojT -> out ----------------
// ROUTED: atomicAdd(out[token], cw * v)   else: out[row] = v (shared, initializes out)
template <bool ROUTED>
__global__ __launch_bounds__(256) void gemm_proj(const unsigned short* __restrict__ Yg,
                                                 const unsigned short* __restrict__ BtAll,
                                                 float* __restrict__ Out,
                                                 const float* __restrict__ cw,
                                                 const int* __restrict__ idx,
                                                 const int* __restrict__ offs,
                                                 const int* __restrict__ cnt) {
  __shared__ __align__(16) unsigned short As[4 * 128 * 8];
  __shared__ __align__(16) unsigned short Bs[4 * 128 * 8];
  const int tid = threadIdx.x;
  const int wave = tid >> 6, lane = tid & 63;

  const int f = blockIdx.y * gridDim.x + blockIdx.x;
  const int cpx = (gridDim.x * gridDim.y) >> 3;
  const int swz = (f & 7) * cpx + (f >> 3);
  const int bx = swz % gridDim.x, by = swz / gridDim.x;

  const int m0 = by * 128, n0 = bx * 128;
  const int e = ROUTED ? blockIdx.z : 0;
  const int cnt_e = ROUTED ? cnt[e] : NTOK;
  if (ROUTED && m0 >= cnt_e) return;
  const int base = ROUTED ? offs[e] : 0;
  const unsigned short* Bt = BtAll + (ROUTED ? (size_t)(e + 1) * WSZ : 0);

  const int q0 = wave * 128 + lane, q1 = q0 + 64;
  const int kg0 = q0 >> 7, r0 = q0 & 127;
  const int kg1 = q1 >> 7, r1 = q1 & 127;
  const unsigned short* gA0 = Yg + (size_t)(base + m0 + r0) * H_DIM + kg0 * 8;
  const unsigned short* gA1 = Yg + (size_t)(base + m0 + r1) * H_DIM + kg1 * 8;
  const unsigned short* gB0 = Bt + (size_t)(n0 + r0) * H_DIM + kg0 * 8;
  const unsigned short* gB1 = Bt + (size_t)(n0 + r1) * H_DIM + kg1 * 8;
  unsigned short* lA0 = &As[(wave * 2 + 0) * 512];
  unsigned short* lA1 = &As[(wave * 2 + 1) * 512];
  unsigned short* lB0 = &Bs[(wave * 2 + 0) * 512];
  unsigned short* lB1 = &Bs[(wave * 2 + 1) * 512];

  const int wr = wave >> 1, wc = wave & 1;
  const int fr = lane & 15, fq = lane >> 4;
  f32x4 acc[4][4] = {};

  for (int k0 = 0; k0 < H_DIM; k0 += 32) {
    gload16(gA0 + k0, lA0);
    gload16(gA1 + k0, lA1);
    gload16(gB0 + k0, lB0);
    gload16(gB1 + k0, lB1);
    __syncthreads();
    bf16x8 af[4], bfr[4];
#pragma unroll
    for (int m = 0; m < 4; ++m)
      af[m] = *(const bf16x8*)&As[fq * 1024 + (wr * 64 + m * 16 + fr) * 8];
#pragma unroll
    for (int n = 0; n < 4; ++n)
      bfr[n] = *(const bf16x8*)&Bs[fq * 1024 + (wc * 64 + n * 16 + fr) * 8];
#pragma unroll
    for (int m = 0; m < 4; ++m)
#pragma unroll
      for (int n = 0; n < 4; ++n)
        acc[m][n] = __builtin_amdgcn_mfma_f32_16x16x32_bf16(af[m], bfr[n], acc[m][n], 0, 0, 0);
    __syncthreads();
  }

#pragma unroll
  for (int m = 0; m < 4; ++m)
#pragma unroll
    for (int n = 0; n < 4; ++n)
#pragma unroll
      for (int j = 0; j < 4; ++j) {
        const int p = wr * 64 + m * 16 + fq * 4 + j;
        const int col = n0 + wc * 64 + n * 16 + fr;
        const float v = acc[m][n][j];
        if (ROUTED) {
          const int gp = m0 + p;
          if (gp < cnt_e) {
            const int t = idx[base + gp];
            const float s = cw[(size_t)t * NR + e];
            atomicAdd(&Out[(size_t)t * C_DIM + col], s * v);
          }
        } else {
          Out[(size_t)(m0 + p) * C_DIM + col] = v;
        }
      }
}

extern "C" void kernel_launch(void* const* d_in, const int* in_sizes, int n_in,
                              void* d_out, int out_size, void* d_ws, size_t ws_size,
                              hipStream_t stream) {
  const float* x            = (const float*)d_in[0];
  const float* gate_w       = (const float*)d_in[1];
  const float* lb_bias      = (const float*)d_in[2];
  const float* shared_wfc   = (const float*)d_in[3];
  const float* shared_wproj = (const float*)d_in[4];
  const float* routed_wfc   = (const float*)d_in[5];
  const float* routed_wproj = (const float*)d_in[6];
  float* out = (float*)d_out;

  char* ws = (char*)d_ws;
  unsigned short* xb     = (unsigned short*)(ws);                       // 16 MiB
  unsigned short* wfcT   = (unsigned short*)(ws + 16777216);            // 64 MiB [8][H][C]
  unsigned short* wprojT = (unsigned short*)(ws + 83886080);            // 64 MiB [8][C][H]
  unsigned short* Yg     = (unsigned short*)(ws + 150994944);           // 136 MiB [MAXG][H]
  float*          cw     = (float*)(ws + 293601280);                    // 224 KiB
  int*            idx    = (int*)(ws + 293830656);                      // 68 KiB
  int*            cnt    = (int*)(ws + 293900288);
  int*            offs   = (int*)(ws + 293900352);
  int*            cursor = (int*)(ws + 293900416);

  cast_x_kernel<<<NTOK * C_DIM / (256 * 4), 256, 0, stream>>>(x, xb);
  init_kernel<<<(MAXG + 255) / 256, 256, 0, stream>>>(idx, cnt, cursor);
  routing_kernel<<<NTOK / 4, 256, 0, stream>>>(x, gate_w, lb_bias, cw, cnt);
  scan_kernel<<<1, 1, 0, stream>>>(cnt, offs);
  place_kernel<<<NTOK / 256, 256, 0, stream>>>(cw, offs, cursor, idx);

  // all-expert weight transposes (e=0 shared, e=1..7 routed)
  transpose_cast_all<<<dim3(H_DIM / 32, C_DIM / 32, 8), dim3(32, 8), 0, stream>>>(
      shared_wfc, routed_wfc, wfcT, C_DIM, H_DIM);
  transpose_cast_all<<<dim3(C_DIM / 32, H_DIM / 32, 8), dim3(32, 8), 0, stream>>>(
      shared_wproj, routed_wproj, wprojT, H_DIM, C_DIM);

  // shared expert (dense): fc -> Yg[0:8192), proj -> out (plain store)
  gemm_fc<false><<<dim3(H_DIM / 128, NTOK / 128, 1), 256, 0, stream>>>(
      xb, wfcT, Yg, idx, offs, cnt);
  gemm_proj<false><<<dim3(C_DIM / 128, NTOK / 128, 1), 256, 0, stream>>>(
      Yg, wprojT, out, cw, idx, offs, cnt);

  // routed experts (gathered, top-2 only): one dispatch each for fc and proj
  gemm_fc<true><<<dim3(H_DIM / 128, NTOK / 128, NR), 256, 0, stream>>>(
      xb, wfcT, Yg, idx, offs, cnt);
  gemm_proj<true><<<dim3(C_DIM / 128, NTOK / 128, NR), 256, 0, stream>>>(
      Yg, wprojT, out, cw, idx, offs, cnt);
}

// Round 3
// 2566.074 us; speedup vs baseline: 1.0389x; 1.0389x over previous
//
#include <hip/hip_runtime.h>
#include <hip/hip_bf16.h>

#define AS1 __attribute__((address_space(1)))
#define AS3 __attribute__((address_space(3)))

typedef __bf16 bf16x8 __attribute__((ext_vector_type(8)));
typedef float f32x4 __attribute__((ext_vector_type(4)));

static constexpr int C_DIM = 1024;
static constexpr int H_DIM = 4096;
static constexpr int NTOK  = 8192;   // 4*2048
static constexpr int NR    = 7;      // routed experts
static constexpr int MAXG  = 17408;  // gathered-row capacity (16384 + 7*128 pad)
static constexpr size_t WSZ = (size_t)C_DIM * H_DIM;  // elems per expert weight

static __device__ __forceinline__ unsigned short f2bf(float f) {
  __hip_bfloat16 h = __float2bfloat16(f);
  return *reinterpret_cast<unsigned short*>(&h);
}

static __device__ __forceinline__ void gload16(const void* g, void* lds) {
  __builtin_amdgcn_global_load_lds((const AS1 void*)g, (AS3 void*)lds, 16, 0, 0);
}

// ---------------- cast x (fp32 -> bf16) ----------------
__global__ __launch_bounds__(256) void cast_x_kernel(const float* __restrict__ x,
                                                     unsigned short* __restrict__ xb) {
  size_t i = ((size_t)blockIdx.x * blockDim.x + threadIdx.x) * 4;
  float4 v = *(const float4*)(x + i);
  ushort4 o;
  o.x = f2bf(v.x); o.y = f2bf(v.y); o.z = f2bf(v.z); o.w = f2bf(v.w);
  *(ushort4*)(xb + i) = o;
}

// ---------------- init: zero idx / cnt / cursor ----------------
__global__ __launch_bounds__(256) void init_kernel(int* __restrict__ idx, int* __restrict__ cnt,
                                                   int* __restrict__ cursor) {
  int i = blockIdx.x * 256 + threadIdx.x;
  if (i < MAXG) idx[i] = 0;
  if (blockIdx.x == 0 && threadIdx.x < 8) { cnt[threadIdx.x] = 0; cursor[threadIdx.x] = 0; }
}

// ---------------- routing: one wave per token; writes cw + counts ----------------
__global__ __launch_bounds__(256) void routing_kernel(const float* __restrict__ x,
                                                      const float* __restrict__ gw,
                                                      const float* __restrict__ bias,
                                                      float* __restrict__ cw,
                                                      int* __restrict__ cnt) {
  int wid = (int)((blockIdx.x * (size_t)blockDim.x + threadIdx.x) >> 6);
  int lane = threadIdx.x & 63;
  if (wid >= NTOK) return;
  const float* xt = x + (size_t)wid * C_DIM;
  float p[NR] = {0.f, 0.f, 0.f, 0.f, 0.f, 0.f, 0.f};
  for (int i = lane; i < C_DIM; i += 64) {
    float xv = xt[i];
#pragma unroll
    for (int e = 0; e < NR; ++e) p[e] += xv * gw[e * C_DIM + i];
  }
#pragma unroll
  for (int e = 0; e < NR; ++e) {
#pragma unroll
    for (int off = 32; off; off >>= 1) p[e] += __shfl_down(p[e], off);
  }
  if (lane == 0) {
    float m = p[0];
#pragma unroll
    for (int e = 1; e < NR; ++e) m = fmaxf(m, p[e]);
    float pr[NR], s = 0.f;
#pragma unroll
    for (int e = 0; e < NR; ++e) { pr[e] = __expf(p[e] - m); s += pr[e]; }
    float inv = 1.0f / s;
#pragma unroll
    for (int e = 0; e < NR; ++e) pr[e] *= inv;
    float sel[NR];
#pragma unroll
    for (int e = 0; e < NR; ++e) sel[e] = p[e] + bias[e];
    int i1 = 0;
#pragma unroll
    for (int e = 1; e < NR; ++e) if (sel[e] > sel[i1]) i1 = e;
    int i2 = -1;
#pragma unroll
    for (int e = 0; e < NR; ++e) {
      if (e == i1) continue;
      if (i2 < 0 || sel[e] > sel[i2]) i2 = e;
    }
    float c[NR] = {0.f, 0.f, 0.f, 0.f, 0.f, 0.f, 0.f};
    c[i1] = pr[i1];
    c[i2] += pr[i2];
#pragma unroll
    for (int e = 0; e < NR; ++e) cw[(size_t)wid * NR + e] = c[e];
    atomicAdd(&cnt[i1], 1);
    atomicAdd(&cnt[i2], 1);
  }
}

// ---------------- scan: tile-aligned exclusive prefix of counts ----------------
__global__ void scan_kernel(const int* __restrict__ cnt, int* __restrict__ offs) {
  int o = 0;
  for (int e = 0; e < NR; ++e) { offs[e] = o; o += (cnt[e] + 127) & ~127; }
}

// ---------------- place: fill gathered index lists + per-token slot/weight ----------------
__global__ __launch_bounds__(256) void place_kernel(const float* __restrict__ cw,
                                                    const int* __restrict__ offs,
                                                    int* __restrict__ cursor,
                                                    int* __restrict__ idx,
                                                    int* __restrict__ tok2slot,
                                                    float* __restrict__ tok2w) {
  int t = blockIdx.x * 256 + threadIdx.x;
  if (t >= NTOK) return;
  int k = 0;
#pragma unroll
  for (int e = 0; e < NR; ++e) {
    float w = cw[(size_t)t * NR + e];
    if (w > 0.f) {
      int p = atomicAdd(&cursor[e], 1);
      int slot = offs[e] + p;
      idx[slot] = t;
      tok2slot[t * 2 + k] = slot;
      tok2w[t * 2 + k] = w;
      ++k;
    }
  }
}

// ---------------- transpose + cast all 8 experts: fp32 [R][S] -> bf16 [S][R] ----------------
__global__ void transpose_cast_all(const float* __restrict__ shared_w,
                                   const float* __restrict__ routed_w,
                                   unsigned short* __restrict__ out, int R, int S) {
  int e = blockIdx.z;
  const float* in = (e == 0) ? shared_w : routed_w + (size_t)(e - 1) * R * S;
  unsigned short* o = out + (size_t)e * R * S;
  __shared__ float t[32][33];
  int bx = blockIdx.x * 32;  // S
  int by = blockIdx.y * 32;  // R
  int tx = threadIdx.x, ty = threadIdx.y;  // (32, 8)
#pragma unroll
  for (int i = 0; i < 32; i += 8)
    t[ty + i][tx] = in[(size_t)(by + ty + i) * S + bx + tx];
  __syncthreads();
#pragma unroll
  for (int i = 0; i < 32; i += 8)
    o[(size_t)(bx + ty + i) * R + by + tx] = f2bf(t[tx][ty + i]);
}

// ---------------- fc GEMM: A rows (gathered) x wfcT -> gelu -> Y (bf16) ----------------
template <bool GATHER>
__global__ __launch_bounds__(256) void gemm_fc(const unsigned short* __restrict__ A,
                                               const unsigned short* __restrict__ BtAll,
                                               unsigned short* __restrict__ Y,
                                               const int* __restrict__ idx,
                                               const int* __restrict__ offs,
                                               const int* __restrict__ cnt) {
  __shared__ __align__(16) unsigned short As[4 * 128 * 8];
  __shared__ __align__(16) unsigned short Bs[4 * 128 * 8];
  const int tid = threadIdx.x;
  const int wave = tid >> 6, lane = tid & 63;

  // bijective XCD swizzle over the xy tile plane (grid xy divisible by 8)
  const int f = blockIdx.y * gridDim.x + blockIdx.x;
  const int cpx = (gridDim.x * gridDim.y) >> 3;
  const int swz = (f & 7) * cpx + (f >> 3);
  const int bx = swz % gridDim.x, by = swz / gridDim.x;

  const int m0 = by * 128, n0 = bx * 128;
  const int e = GATHER ? blockIdx.z : 0;
  const int cnt_e = GATHER ? cnt[e] : NTOK;
  if (GATHER && m0 >= cnt_e) return;
  const int base = GATHER ? offs[e] : 0;
  const unsigned short* Bt = BtAll + (GATHER ? (size_t)(e + 1) * WSZ : 0);

  // loop-invariant staging assignment: 2 chunks/thread, fixed (kg,row)
  const int q0 = wave * 128 + lane, q1 = q0 + 64;
  const int kg0 = q0 >> 7, r0 = q0 & 127;
  const int kg1 = q1 >> 7, r1 = q1 & 127;
  const size_t rowA0 = GATHER ? (size_t)idx[base + m0 + r0] : (size_t)(m0 + r0);
  const size_t rowA1 = GATHER ? (size_t)idx[base + m0 + r1] : (size_t)(m0 + r1);
  const unsigned short* gA0 = A + rowA0 * C_DIM + kg0 * 8;
  const unsigned short* gA1 = A + rowA1 * C_DIM + kg1 * 8;
  const unsigned short* gB0 = Bt + (size_t)(n0 + r0) * C_DIM + kg0 * 8;
  const unsigned short* gB1 = Bt + (size_t)(n0 + r1) * C_DIM + kg1 * 8;
  unsigned short* lA0 = &As[(wave * 2 + 0) * 512];
  unsigned short* lA1 = &As[(wave * 2 + 1) * 512];
  unsigned short* lB0 = &Bs[(wave * 2 + 0) * 512];
  unsigned short* lB1 = &Bs[(wave * 2 + 1) * 512];

  const int wr = wave >> 1, wc = wave & 1;
  const int fr = lane & 15, fq = lane >> 4;
  f32x4 acc[4][4] = {};

  for (int k0 = 0; k0 < C_DIM; k0 += 32) {
    gload16(gA0 + k0, lA0);
    gload16(gA1 + k0, lA1);
    gload16(gB0 + k0, lB0);
    gload16(gB1 + k0, lB1);
    __syncthreads();
    bf16x8 af[4], bfr[4];
#pragma unroll
    for (int m = 0; m < 4; ++m)
      af[m] = *(const bf16x8*)&As[fq * 1024 + (wr * 64 + m * 16 + fr) * 8];
#pragma unroll
    for (int n = 0; n < 4; ++n)
      bfr[n] = *(const bf16x8*)&Bs[fq * 1024 + (wc * 64 + n * 16 + fr) * 8];
#pragma unroll
    for (int m = 0; m < 4; ++m)
#pragma unroll
      for (int n = 0; n < 4; ++n)
        acc[m][n] = __builtin_amdgcn_mfma_f32_16x16x32_bf16(af[m], bfr[n], acc[m][n], 0, 0, 0);
    __syncthreads();
  }

#pragma unroll
  for (int m = 0; m < 4; ++m)
#pragma unroll
    for (int n = 0; n < 4; ++n)
#pragma unroll
      for (int j = 0; j < 4; ++j) {
        const int row = m0 + wr * 64 + m * 16 + fq * 4 + j;
        const int col = n0 + wc * 64 + n * 16 + fr;
        const float v = acc[m][n][j];
        const float g = 0.5f * v * (1.0f + erff(v * 0.70710678118654752f));
        Y[(size_t)(base + row) * H_DIM + col] = f2bf(g);
      }
}

// ---------------- proj GEMM: Y x wprojT ----------------
// ROUTED: plain store raw v into Yout[slot][C]   else: out[row] = v (shared)
template <bool ROUTED>
__global__ __launch_bounds__(256) void gemm_proj(const unsigned short* __restrict__ Yg,
                                                 const unsigned short* __restrict__ BtAll,
                                                 float* __restrict__ Out,
                                                 const int* __restrict__ offs,
                                                 const int* __restrict__ cnt) {
  __shared__ __align__(16) unsigned short As[4 * 128 * 8];
  __shared__ __align__(16) unsigned short Bs[4 * 128 * 8];
  const int tid = threadIdx.x;
  const int wave = tid >> 6, lane = tid & 63;

  const int f = blockIdx.y * gridDim.x + blockIdx.x;
  const int cpx = (gridDim.x * gridDim.y) >> 3;
  const int swz = (f & 7) * cpx + (f >> 3);
  const int bx = swz % gridDim.x, by = swz / gridDim.x;

  const int m0 = by * 128, n0 = bx * 128;
  const int e = ROUTED ? blockIdx.z : 0;
  const int cnt_e = ROUTED ? cnt[e] : NTOK;
  if (ROUTED && m0 >= cnt_e) return;
  const int base = ROUTED ? offs[e] : 0;
  const unsigned short* Bt = BtAll + (ROUTED ? (size_t)(e + 1) * WSZ : 0);

  const int q0 = wave * 128 + lane, q1 = q0 + 64;
  const int kg0 = q0 >> 7, r0 = q0 & 127;
  const int kg1 = q1 >> 7, r1 = q1 & 127;
  const unsigned short* gA0 = Yg + (size_t)(base + m0 + r0) * H_DIM + kg0 * 8;
  const unsigned short* gA1 = Yg + (size_t)(base + m0 + r1) * H_DIM + kg1 * 8;
  const unsigned short* gB0 = Bt + (size_t)(n0 + r0) * H_DIM + kg0 * 8;
  const unsigned short* gB1 = Bt + (size_t)(n0 + r1) * H_DIM + kg1 * 8;
  unsigned short* lA0 = &As[(wave * 2 + 0) * 512];
  unsigned short* lA1 = &As[(wave * 2 + 1) * 512];
  unsigned short* lB0 = &Bs[(wave * 2 + 0) * 512];
  unsigned short* lB1 = &Bs[(wave * 2 + 1) * 512];

  const int wr = wave >> 1, wc = wave & 1;
  const int fr = lane & 15, fq = lane >> 4;
  f32x4 acc[4][4] = {};

  for (int k0 = 0; k0 < H_DIM; k0 += 32) {
    gload16(gA0 + k0, lA0);
    gload16(gA1 + k0, lA1);
    gload16(gB0 + k0, lB0);
    gload16(gB1 + k0, lB1);
    __syncthreads();
    bf16x8 af[4], bfr[4];
#pragma unroll
    for (int m = 0; m < 4; ++m)
      af[m] = *(const bf16x8*)&As[fq * 1024 + (wr * 64 + m * 16 + fr) * 8];
#pragma unroll
    for (int n = 0; n < 4; ++n)
      bfr[n] = *(const bf16x8*)&Bs[fq * 1024 + (wc * 64 + n * 16 + fr) * 8];
#pragma unroll
    for (int m = 0; m < 4; ++m)
#pragma unroll
      for (int n = 0; n < 4; ++n)
        acc[m][n] = __builtin_amdgcn_mfma_f32_16x16x32_bf16(af[m], bfr[n], acc[m][n], 0, 0, 0);
    __syncthreads();
  }

#pragma unroll
  for (int m = 0; m < 4; ++m)
#pragma unroll
    for (int n = 0; n < 4; ++n)
#pragma unroll
      for (int j = 0; j < 4; ++j) {
        const int p = wr * 64 + m * 16 + fq * 4 + j;
        const int col = n0 + wc * 64 + n * 16 + fr;
        const float v = acc[m][n][j];
        // ROUTED: Out == Yout (per-slot buffer); else Out == d_out (row == token)
        Out[(size_t)(base + m0 + p) * C_DIM + col] = v;
      }
}

// ---------------- combine: out[t] += w0*Yout[slot0] + w1*Yout[slot1] ----------------
__global__ __launch_bounds__(256) void combine_kernel(const float* __restrict__ Yout,
                                                      const int* __restrict__ tok2slot,
                                                      const float* __restrict__ tok2w,
                                                      float* __restrict__ out) {
  const int t = blockIdx.x;          // one block per token (C=1024 = 256 float4)
  const int c4 = threadIdx.x;
  const int s0 = tok2slot[t * 2], s1 = tok2slot[t * 2 + 1];
  const float w0 = tok2w[t * 2], w1 = tok2w[t * 2 + 1];
  const float4 a = ((const float4*)(Yout + (size_t)s0 * C_DIM))[c4];
  const float4 b = ((const float4*)(Yout + (size_t)s1 * C_DIM))[c4];
  float4 o = ((float4*)(out + (size_t)t * C_DIM))[c4];
  o.x += w0 * a.x + w1 * b.x;
  o.y += w0 * a.y + w1 * b.y;
  o.z += w0 * a.z + w1 * b.z;
  o.w += w0 * a.w + w1 * b.w;
  ((float4*)(out + (size_t)t * C_DIM))[c4] = o;
}

extern "C" void kernel_launch(void* const* d_in, const int* in_sizes, int n_in,
                              void* d_out, int out_size, void* d_ws, size_t ws_size,
                              hipStream_t stream) {
  const float* x            = (const float*)d_in[0];
  const float* gate_w       = (const float*)d_in[1];
  const float* lb_bias      = (const float*)d_in[2];
  const float* shared_wfc   = (const float*)d_in[3];
  const float* shared_wproj = (const float*)d_in[4];
  const float* routed_wfc   = (const float*)d_in[5];
  const float* routed_wproj = (const float*)d_in[6];
  float* out = (float*)d_out;

  char* ws = (char*)d_ws;
  unsigned short* xb     = (unsigned short*)(ws);                 // 16 MiB (dead after routed fc)
  unsigned short* wfcT   = (unsigned short*)(ws + 16777216);      // 64 MiB (dead after routed fc)
  float*          Yout   = (float*)(ws);                          // 68 MiB, OVERLAYS xb+wfcT (80 MiB)
  unsigned short* wprojT = (unsigned short*)(ws + 83886080);      // 64 MiB [8][C][H]
  unsigned short* Yg     = (unsigned short*)(ws + 150994944);     // 136 MiB [MAXG][H]
  float*          cw     = (float*)(ws + 293601280);              // 224 KiB
  int*            idx    = (int*)(ws + 293830656);                // 68 KiB
  int*            cnt    = (int*)(ws + 293900288);
  int*            offs   = (int*)(ws + 293900352);
  int*            cursor = (int*)(ws + 293900416);
  int*            tok2slot = (int*)(ws + 293900480);              // 64 KiB
  float*          tok2w    = (float*)(ws + 293966016);            // 64 KiB

  cast_x_kernel<<<NTOK * C_DIM / (256 * 4), 256, 0, stream>>>(x, xb);
  init_kernel<<<(MAXG + 255) / 256, 256, 0, stream>>>(idx, cnt, cursor);
  routing_kernel<<<NTOK / 4, 256, 0, stream>>>(x, gate_w, lb_bias, cw, cnt);
  scan_kernel<<<1, 1, 0, stream>>>(cnt, offs);
  place_kernel<<<NTOK / 256, 256, 0, stream>>>(cw, offs, cursor, idx, tok2slot, tok2w);

  // all-expert weight transposes (e=0 shared, e=1..7 routed)
  transpose_cast_all<<<dim3(H_DIM / 32, C_DIM / 32, 8), dim3(32, 8), 0, stream>>>(
      shared_wfc, routed_wfc, wfcT, C_DIM, H_DIM);
  transpose_cast_all<<<dim3(C_DIM / 32, H_DIM / 32, 8), dim3(32, 8), 0, stream>>>(
      shared_wproj, routed_wproj, wprojT, H_DIM, C_DIM);

  // shared expert (dense): fc -> Yg[0:8192), proj -> out (plain store)
  gemm_fc<false><<<dim3(H_DIM / 128, NTOK / 128, 1), 256, 0, stream>>>(
      xb, wfcT, Yg, idx, offs, cnt);
  gemm_proj<false><<<dim3(C_DIM / 128, NTOK / 128, 1), 256, 0, stream>>>(
      Yg, wprojT, out, offs, cnt);

  // routed experts (gathered, top-2): fc reads xb/wfcT, THEN proj overlays Yout on them
  gemm_fc<true><<<dim3(H_DIM / 128, NTOK / 128, NR), 256, 0, stream>>>(
      xb, wfcT, Yg, idx, offs, cnt);
  gemm_proj<true><<<dim3(C_DIM / 128, NTOK / 128, NR), 256, 0, stream>>>(
      Yg, wprojT, Yout, offs, cnt);

  // out[t] += w0*Yout[slot0] + w1*Yout[slot1]
  combine_kernel<<<NTOK, 256, 0, stream>>>(Yout, tok2slot, tok2w, out);
}

// Round 4
// 1341.613 us; speedup vs baseline: 1.9872x; 1.9127x over previous
//
#include <hip/hip_runtime.h>
#include <hip/hip_bf16.h>

#define AS1 __attribute__((address_space(1)))
#define AS3 __attribute__((address_space(3)))

typedef __bf16 bf16x8 __attribute__((ext_vector_type(8)));
typedef float f32x4 __attribute__((ext_vector_type(4)));

static constexpr int C_DIM = 1024;
static constexpr int H_DIM = 4096;
static constexpr int NTOK  = 8192;   // 4*2048
static constexpr int NR    = 7;      // routed experts
static constexpr int MAXG  = 17408;  // gathered-row capacity (>= 135*128)
static constexpr int MAXT  = 136;    // max m-tiles across routed experts
static constexpr size_t WSZ = (size_t)C_DIM * H_DIM;  // elems per expert weight

static __device__ __forceinline__ unsigned short f2bf(float f) {
  __hip_bfloat16 h = __float2bfloat16(f);
  return *reinterpret_cast<unsigned short*>(&h);
}

static __device__ __forceinline__ void gload16(const void* g, void* lds) {
  __builtin_amdgcn_global_load_lds((const AS1 void*)g, (AS3 void*)lds, 16, 0, 0);
}

// ---------------- cast x (fp32 -> bf16) ----------------
__global__ __launch_bounds__(256) void cast_x_kernel(const float* __restrict__ x,
                                                     unsigned short* __restrict__ xb) {
  size_t i = ((size_t)blockIdx.x * blockDim.x + threadIdx.x) * 4;
  float4 v = *(const float4*)(x + i);
  ushort4 o;
  o.x = f2bf(v.x); o.y = f2bf(v.y); o.z = f2bf(v.z); o.w = f2bf(v.w);
  *(ushort4*)(xb + i) = o;
}

// ---------------- init: zero idx / cnt / cursor ----------------
__global__ __launch_bounds__(256) void init_kernel(int* __restrict__ idx, int* __restrict__ cnt,
                                                   int* __restrict__ cursor) {
  int i = blockIdx.x * 256 + threadIdx.x;
  if (i < MAXG) idx[i] = 0;
  if (blockIdx.x == 0 && threadIdx.x < 8) { cnt[threadIdx.x] = 0; cursor[threadIdx.x] = 0; }
}

// ---------------- routing: one wave per token; writes cw + counts ----------------
__global__ __launch_bounds__(256) void routing_kernel(const float* __restrict__ x,
                                                      const float* __restrict__ gw,
                                                      const float* __restrict__ bias,
                                                      float* __restrict__ cw,
                                                      int* __restrict__ cnt) {
  int wid = (int)((blockIdx.x * (size_t)blockDim.x + threadIdx.x) >> 6);
  int lane = threadIdx.x & 63;
  if (wid >= NTOK) return;
  const float* xt = x + (size_t)wid * C_DIM;
  float p[NR] = {0.f, 0.f, 0.f, 0.f, 0.f, 0.f, 0.f};
  for (int i = lane; i < C_DIM; i += 64) {
    float xv = xt[i];
#pragma unroll
    for (int e = 0; e < NR; ++e) p[e] += xv * gw[e * C_DIM + i];
  }
#pragma unroll
  for (int e = 0; e < NR; ++e) {
#pragma unroll
    for (int off = 32; off; off >>= 1) p[e] += __shfl_down(p[e], off);
  }
  if (lane == 0) {
    float m = p[0];
#pragma unroll
    for (int e = 1; e < NR; ++e) m = fmaxf(m, p[e]);
    float pr[NR], s = 0.f;
#pragma unroll
    for (int e = 0; e < NR; ++e) { pr[e] = __expf(p[e] - m); s += pr[e]; }
    float inv = 1.0f / s;
#pragma unroll
    for (int e = 0; e < NR; ++e) pr[e] *= inv;
    float sel[NR];
#pragma unroll
    for (int e = 0; e < NR; ++e) sel[e] = p[e] + bias[e];
    int i1 = 0;
#pragma unroll
    for (int e = 1; e < NR; ++e) if (sel[e] > sel[i1]) i1 = e;
    int i2 = -1;
#pragma unroll
    for (int e = 0; e < NR; ++e) {
      if (e == i1) continue;
      if (i2 < 0 || sel[e] > sel[i2]) i2 = e;
    }
    float c[NR] = {0.f, 0.f, 0.f, 0.f, 0.f, 0.f, 0.f};
    c[i1] = pr[i1];
    c[i2] += pr[i2];
#pragma unroll
    for (int e = 0; e < NR; ++e) cw[(size_t)wid * NR + e] = c[e];
    atomicAdd(&cnt[i1], 1);
    atomicAdd(&cnt[i2], 1);
  }
}

// ---------------- scan: offsets + compact tile map ----------------
__global__ void scan_kernel(const int* __restrict__ cnt, int* __restrict__ offs,
                            int* __restrict__ tmap, int* __restrict__ ntiles) {
  int o = 0, nt = 0;
  for (int e = 0; e < NR; ++e) {
    offs[e] = o;
    int n = (cnt[e] + 127) & ~127;
    o += n;
    for (int tm = 0; tm < n; tm += 128) tmap[nt++] = (e << 16) | tm;
  }
  *ntiles = nt;
}

// ---------------- place: fill gathered index lists + per-token slot/weight ----------------
__global__ __launch_bounds__(256) void place_kernel(const float* __restrict__ cw,
                                                    const int* __restrict__ offs,
                                                    int* __restrict__ cursor,
                                                    int* __restrict__ idx,
                                                    int* __restrict__ tok2slot,
                                                    float* __restrict__ tok2w) {
  int t = blockIdx.x * 256 + threadIdx.x;
  if (t >= NTOK) return;
  int k = 0;
#pragma unroll
  for (int e = 0; e < NR; ++e) {
    float w = cw[(size_t)t * NR + e];
    if (w > 0.f) {
      int p = atomicAdd(&cursor[e], 1);
      int slot = offs[e] + p;
      idx[slot] = t;
      tok2slot[t * 2 + k] = slot;
      tok2w[t * 2 + k] = w;
      ++k;
    }
  }
}

// ---------------- transpose + cast all 8 experts: fp32 [R][S] -> bf16 [S][R] ----------------
__global__ void transpose_cast_all(const float* __restrict__ shared_w,
                                   const float* __restrict__ routed_w,
                                   unsigned short* __restrict__ out, int R, int S) {
  int e = blockIdx.z;
  const float* in = (e == 0) ? shared_w : routed_w + (size_t)(e - 1) * R * S;
  unsigned short* o = out + (size_t)e * R * S;
  __shared__ float t[32][33];
  int bx = blockIdx.x * 32;  // S
  int by = blockIdx.y * 32;  // R
  int tx = threadIdx.x, ty = threadIdx.y;  // (32, 8)
#pragma unroll
  for (int i = 0; i < 32; i += 8)
    t[ty + i][tx] = in[(size_t)(by + ty + i) * S + bx + tx];
  __syncthreads();
#pragma unroll
  for (int i = 0; i < 32; i += 8)
    o[(size_t)(bx + ty + i) * R + by + tx] = f2bf(t[tx][ty + i]);
}

// ---------------- fc GEMM: A rows (gathered) x wfcT -> gelu -> Y (bf16) ----------------
template <bool GATHER>
__global__ __launch_bounds__(256) void gemm_fc(const unsigned short* __restrict__ A,
                                               const unsigned short* __restrict__ BtAll,
                                               unsigned short* __restrict__ Y,
                                               const int* __restrict__ idx,
                                               const int* __restrict__ offs,
                                               const int* __restrict__ tmap,
                                               const int* __restrict__ ntiles) {
  __shared__ __align__(16) unsigned short As[4 * 128 * 8];
  __shared__ __align__(16) unsigned short Bs[4 * 128 * 8];
  const int tid = threadIdx.x;
  const int wave = tid >> 6, lane = tid & 63;

  int m0, n0, base;
  const unsigned short* Bt;
  if (GATHER) {
    if (blockIdx.y >= *ntiles) return;
    const int packed = tmap[blockIdx.y];
    const int e = packed >> 16;
    m0 = packed & 0xffff;
    n0 = blockIdx.x * 128;
    base = offs[e];
    Bt = BtAll + (size_t)(e + 1) * WSZ;
  } else {
    // bijective XCD swizzle (dense grid, fully live)
    const int f = blockIdx.y * gridDim.x + blockIdx.x;
    const int cpx = (gridDim.x * gridDim.y) >> 3;
    const int swz = (f & 7) * cpx + (f >> 3);
    m0 = (swz / gridDim.x) * 128;
    n0 = (swz % gridDim.x) * 128;
    base = 0;
    Bt = BtAll;
  }

  // loop-invariant staging assignment: 2 chunks/thread, fixed (kg,row)
  const int q0 = wave * 128 + lane, q1 = q0 + 64;
  const int kg0 = q0 >> 7, r0 = q0 & 127;
  const int kg1 = q1 >> 7, r1 = q1 & 127;
  const size_t rowA0 = GATHER ? (size_t)idx[base + m0 + r0] : (size_t)(m0 + r0);
  const size_t rowA1 = GATHER ? (size_t)idx[base + m0 + r1] : (size_t)(m0 + r1);
  const unsigned short* gA0 = A + rowA0 * C_DIM + kg0 * 8;
  const unsigned short* gA1 = A + rowA1 * C_DIM + kg1 * 8;
  const unsigned short* gB0 = Bt + (size_t)(n0 + r0) * C_DIM + kg0 * 8;
  const unsigned short* gB1 = Bt + (size_t)(n0 + r1) * C_DIM + kg1 * 8;
  unsigned short* lA0 = &As[(wave * 2 + 0) * 512];
  unsigned short* lA1 = &As[(wave * 2 + 1) * 512];
  unsigned short* lB0 = &Bs[(wave * 2 + 0) * 512];
  unsigned short* lB1 = &Bs[(wave * 2 + 1) * 512];

  const int wr = wave >> 1, wc = wave & 1;
  const int fr = lane & 15, fq = lane >> 4;
  f32x4 acc[4][4] = {};

  for (int k0 = 0; k0 < C_DIM; k0 += 32) {
    gload16(gA0 + k0, lA0);
    gload16(gA1 + k0, lA1);
    gload16(gB0 + k0, lB0);
    gload16(gB1 + k0, lB1);
    __syncthreads();
    bf16x8 af[4], bfr[4];
#pragma unroll
    for (int m = 0; m < 4; ++m)
      af[m] = *(const bf16x8*)&As[fq * 1024 + (wr * 64 + m * 16 + fr) * 8];
#pragma unroll
    for (int n = 0; n < 4; ++n)
      bfr[n] = *(const bf16x8*)&Bs[fq * 1024 + (wc * 64 + n * 16 + fr) * 8];
#pragma unroll
    for (int m = 0; m < 4; ++m)
#pragma unroll
      for (int n = 0; n < 4; ++n)
        acc[m][n] = __builtin_amdgcn_mfma_f32_16x16x32_bf16(af[m], bfr[n], acc[m][n], 0, 0, 0);
    __syncthreads();
  }

#pragma unroll
  for (int m = 0; m < 4; ++m)
#pragma unroll
    for (int n = 0; n < 4; ++n)
#pragma unroll
      for (int j = 0; j < 4; ++j) {
        const int row = m0 + wr * 64 + m * 16 + fq * 4 + j;
        const int col = n0 + wc * 64 + n * 16 + fr;
        const float v = acc[m][n][j];
        const float g = 0.5f * v * (1.0f + erff(v * 0.70710678118654752f));
        Y[(size_t)(base + row) * H_DIM + col] = f2bf(g);
      }
}

// ---------------- proj GEMM: Y x wprojT ----------------
// ROUTED: plain store raw v into Yout[slot][C]   else: out[row] = v (shared)
template <bool ROUTED>
__global__ __launch_bounds__(256) void gemm_proj(const unsigned short* __restrict__ Yg,
                                                 const unsigned short* __restrict__ BtAll,
                                                 float* __restrict__ Out,
                                                 const int* __restrict__ offs,
                                                 const int* __restrict__ tmap,
                                                 const int* __restrict__ ntiles) {
  __shared__ __align__(16) unsigned short As[4 * 128 * 8];
  __shared__ __align__(16) unsigned short Bs[4 * 128 * 8];
  const int tid = threadIdx.x;
  const int wave = tid >> 6, lane = tid & 63;

  int m0, n0, base;
  const unsigned short* Bt;
  if (ROUTED) {
    if (blockIdx.y >= *ntiles) return;
    const int packed = tmap[blockIdx.y];
    const int e = packed >> 16;
    m0 = packed & 0xffff;
    n0 = blockIdx.x * 128;
    base = offs[e];
    Bt = BtAll + (size_t)(e + 1) * WSZ;
  } else {
    const int f = blockIdx.y * gridDim.x + blockIdx.x;
    const int cpx = (gridDim.x * gridDim.y) >> 3;
    const int swz = (f & 7) * cpx + (f >> 3);
    m0 = (swz / gridDim.x) * 128;
    n0 = (swz % gridDim.x) * 128;
    base = 0;
    Bt = BtAll;
  }

  const int q0 = wave * 128 + lane, q1 = q0 + 64;
  const int kg0 = q0 >> 7, r0 = q0 & 127;
  const int kg1 = q1 >> 7, r1 = q1 & 127;
  const unsigned short* gA0 = Yg + (size_t)(base + m0 + r0) * H_DIM + kg0 * 8;
  const unsigned short* gA1 = Yg + (size_t)(base + m0 + r1) * H_DIM + kg1 * 8;
  const unsigned short* gB0 = Bt + (size_t)(n0 + r0) * H_DIM + kg0 * 8;
  const unsigned short* gB1 = Bt + (size_t)(n0 + r1) * H_DIM + kg1 * 8;
  unsigned short* lA0 = &As[(wave * 2 + 0) * 512];
  unsigned short* lA1 = &As[(wave * 2 + 1) * 512];
  unsigned short* lB0 = &Bs[(wave * 2 + 0) * 512];
  unsigned short* lB1 = &Bs[(wave * 2 + 1) * 512];

  const int wr = wave >> 1, wc = wave & 1;
  const int fr = lane & 15, fq = lane >> 4;
  f32x4 acc[4][4] = {};

  for (int k0 = 0; k0 < H_DIM; k0 += 32) {
    gload16(gA0 + k0, lA0);
    gload16(gA1 + k0, lA1);
    gload16(gB0 + k0, lB0);
    gload16(gB1 + k0, lB1);
    __syncthreads();
    bf16x8 af[4], bfr[4];
#pragma unroll
    for (int m = 0; m < 4; ++m)
      af[m] = *(const bf16x8*)&As[fq * 1024 + (wr * 64 + m * 16 + fr) * 8];
#pragma unroll
    for (int n = 0; n < 4; ++n)
      bfr[n] = *(const bf16x8*)&Bs[fq * 1024 + (wc * 64 + n * 16 + fr) * 8];
#pragma unroll
    for (int m = 0; m < 4; ++m)
#pragma unroll
      for (int n = 0; n < 4; ++n)
        acc[m][n] = __builtin_amdgcn_mfma_f32_16x16x32_bf16(af[m], bfr[n], acc[m][n], 0, 0, 0);
    __syncthreads();
  }

#pragma unroll
  for (int m = 0; m < 4; ++m)
#pragma unroll
    for (int n = 0; n < 4; ++n)
#pragma unroll
      for (int j = 0; j < 4; ++j) {
        const int p = wr * 64 + m * 16 + fq * 4 + j;
        const int col = n0 + wc * 64 + n * 16 + fr;
        const float v = acc[m][n][j];
        // ROUTED: Out == Yout (per-slot buffer); else Out == d_out (row == token)
        Out[(size_t)(base + m0 + p) * C_DIM + col] = v;
      }
}

// ---------------- combine: out[t] += w0*Yout[slot0] + w1*Yout[slot1] ----------------
__global__ __launch_bounds__(256) void combine_kernel(const float* __restrict__ Yout,
                                                      const int* __restrict__ tok2slot,
                                                      const float* __restrict__ tok2w,
                                                      float* __restrict__ out) {
  const int t = blockIdx.x;          // one block per token (C=1024 = 256 float4)
  const int c4 = threadIdx.x;
  const int s0 = tok2slot[t * 2], s1 = tok2slot[t * 2 + 1];
  const float w0 = tok2w[t * 2], w1 = tok2w[t * 2 + 1];
  const float4 a = ((const float4*)(Yout + (size_t)s0 * C_DIM))[c4];
  const float4 b = ((const float4*)(Yout + (size_t)s1 * C_DIM))[c4];
  float4 o = ((float4*)(out + (size_t)t * C_DIM))[c4];
  o.x += w0 * a.x + w1 * b.x;
  o.y += w0 * a.y + w1 * b.y;
  o.z += w0 * a.z + w1 * b.z;
  o.w += w0 * a.w + w1 * b.w;
  ((float4*)(out + (size_t)t * C_DIM))[c4] = o;
}

extern "C" void kernel_launch(void* const* d_in, const int* in_sizes, int n_in,
                              void* d_out, int out_size, void* d_ws, size_t ws_size,
                              hipStream_t stream) {
  const float* x            = (const float*)d_in[0];
  const float* gate_w       = (const float*)d_in[1];
  const float* lb_bias      = (const float*)d_in[2];
  const float* shared_wfc   = (const float*)d_in[3];
  const float* shared_wproj = (const float*)d_in[4];
  const float* routed_wfc   = (const float*)d_in[5];
  const float* routed_wproj = (const float*)d_in[6];
  float* out = (float*)d_out;

  char* ws = (char*)d_ws;
  unsigned short* xb     = (unsigned short*)(ws);                 // 16 MiB (dead after routed fc)
  unsigned short* wfcT   = (unsigned short*)(ws + 16777216);      // 64 MiB (dead after routed fc)
  float*          Yout   = (float*)(ws);                          // 68 MiB, OVERLAYS xb+wfcT (80 MiB)
  unsigned short* wprojT = (unsigned short*)(ws + 83886080);      // 64 MiB [8][C][H]
  unsigned short* Yg     = (unsigned short*)(ws + 150994944);     // 136 MiB [MAXG][H]
  float*          cw     = (float*)(ws + 293601280);              // 224 KiB
  int*            idx    = (int*)(ws + 293830656);                // 68 KiB
  int*            cnt    = (int*)(ws + 293900288);
  int*            offs   = (int*)(ws + 293900352);
  int*            cursor = (int*)(ws + 293900416);
  int*            tok2slot = (int*)(ws + 293900480);              // 64 KiB
  float*          tok2w    = (float*)(ws + 293966016);            // 64 KiB
  int*            tmap     = (int*)(ws + 294031552);              // 544 B
  int*            ntiles   = (int*)(ws + 294032128);

  cast_x_kernel<<<NTOK * C_DIM / (256 * 4), 256, 0, stream>>>(x, xb);
  init_kernel<<<(MAXG + 255) / 256, 256, 0, stream>>>(idx, cnt, cursor);
  routing_kernel<<<NTOK / 4, 256, 0, stream>>>(x, gate_w, lb_bias, cw, cnt);
  scan_kernel<<<1, 1, 0, stream>>>(cnt, offs, tmap, ntiles);
  place_kernel<<<NTOK / 256, 256, 0, stream>>>(cw, offs, cursor, idx, tok2slot, tok2w);

  // all-expert weight transposes (e=0 shared, e=1..7 routed)
  transpose_cast_all<<<dim3(H_DIM / 32, C_DIM / 32, 8), dim3(32, 8), 0, stream>>>(
      shared_wfc, routed_wfc, wfcT, C_DIM, H_DIM);
  transpose_cast_all<<<dim3(C_DIM / 32, H_DIM / 32, 8), dim3(32, 8), 0, stream>>>(
      shared_wproj, routed_wproj, wprojT, H_DIM, C_DIM);

  // shared expert (dense): fc -> Yg[0:8192), proj -> out (plain store)
  gemm_fc<false><<<dim3(H_DIM / 128, NTOK / 128), 256, 0, stream>>>(
      xb, wfcT, Yg, idx, offs, tmap, ntiles);
  gemm_proj<false><<<dim3(C_DIM / 128, NTOK / 128), 256, 0, stream>>>(
      Yg, wprojT, out, offs, tmap, ntiles);

  // routed experts (gathered, top-2): compact tile grid, every block live
  gemm_fc<true><<<dim3(H_DIM / 128, MAXT), 256, 0, stream>>>(
      xb, wfcT, Yg, idx, offs, tmap, ntiles);
  gemm_proj<true><<<dim3(C_DIM / 128, MAXT), 256, 0, stream>>>(
      Yg, wprojT, Yout, offs, tmap, ntiles);

  // out[t] += w0*Yout[slot0] + w1*Yout[slot1]
  combine_kernel<<<NTOK, 256, 0, stream>>>(Yout, tok2slot, tok2w, out);
}

// Round 5
// 1338.136 us; speedup vs baseline: 1.9923x; 1.0026x over previous
//
#include <hip/hip_runtime.h>
#include <hip/hip_bf16.h>

#define AS1 __attribute__((address_space(1)))
#define AS3 __attribute__((address_space(3)))

typedef __bf16 bf16x8 __attribute__((ext_vector_type(8)));
typedef float f32x4 __attribute__((ext_vector_type(4)));

static constexpr int C_DIM = 1024;
static constexpr int H_DIM = 4096;
static constexpr int NTOK  = 8192;   // 4*2048
static constexpr int NR    = 7;      // routed experts
static constexpr int MAXG  = 17408;  // gathered-row capacity (>= 135*128)
static constexpr int MAXT  = 136;    // max m-tiles across routed experts
static constexpr size_t WSZ = (size_t)C_DIM * H_DIM;  // elems per expert weight

static __device__ __forceinline__ unsigned short f2bf(float f) {
  __hip_bfloat16 h = __float2bfloat16(f);
  return *reinterpret_cast<unsigned short*>(&h);
}

static __device__ __forceinline__ void gload16(const void* g, void* lds) {
  __builtin_amdgcn_global_load_lds((const AS1 void*)g, (AS3 void*)lds, 16, 0, 0);
}

// ---------------- cast x (fp32 -> bf16) ----------------
__global__ __launch_bounds__(256) void cast_x_kernel(const float* __restrict__ x,
                                                     unsigned short* __restrict__ xb) {
  size_t i = ((size_t)blockIdx.x * blockDim.x + threadIdx.x) * 4;
  float4 v = *(const float4*)(x + i);
  ushort4 o;
  o.x = f2bf(v.x); o.y = f2bf(v.y); o.z = f2bf(v.z); o.w = f2bf(v.w);
  *(ushort4*)(xb + i) = o;
}

// ---------------- init: zero idx / cnt / cursor ----------------
__global__ __launch_bounds__(256) void init_kernel(int* __restrict__ idx, int* __restrict__ cnt,
                                                   int* __restrict__ cursor) {
  int i = blockIdx.x * 256 + threadIdx.x;
  if (i < MAXG) idx[i] = 0;
  if (blockIdx.x == 0 && threadIdx.x < 8) { cnt[threadIdx.x] = 0; cursor[threadIdx.x] = 0; }
}

// ---------------- routing: one wave per token; writes cw + counts ----------------
__global__ __launch_bounds__(256) void routing_kernel(const float* __restrict__ x,
                                                      const float* __restrict__ gw,
                                                      const float* __restrict__ bias,
                                                      float* __restrict__ cw,
                                                      int* __restrict__ cnt) {
  int wid = (int)((blockIdx.x * (size_t)blockDim.x + threadIdx.x) >> 6);
  int lane = threadIdx.x & 63;
  if (wid >= NTOK) return;
  const float* xt = x + (size_t)wid * C_DIM;
  float p[NR] = {0.f, 0.f, 0.f, 0.f, 0.f, 0.f, 0.f};
  for (int i = lane; i < C_DIM; i += 64) {
    float xv = xt[i];
#pragma unroll
    for (int e = 0; e < NR; ++e) p[e] += xv * gw[e * C_DIM + i];
  }
#pragma unroll
  for (int e = 0; e < NR; ++e) {
#pragma unroll
    for (int off = 32; off; off >>= 1) p[e] += __shfl_down(p[e], off);
  }
  if (lane == 0) {
    float m = p[0];
#pragma unroll
    for (int e = 1; e < NR; ++e) m = fmaxf(m, p[e]);
    float pr[NR], s = 0.f;
#pragma unroll
    for (int e = 0; e < NR; ++e) { pr[e] = __expf(p[e] - m); s += pr[e]; }
    float inv = 1.0f / s;
#pragma unroll
    for (int e = 0; e < NR; ++e) pr[e] *= inv;
    float sel[NR];
#pragma unroll
    for (int e = 0; e < NR; ++e) sel[e] = p[e] + bias[e];
    int i1 = 0;
#pragma unroll
    for (int e = 1; e < NR; ++e) if (sel[e] > sel[i1]) i1 = e;
    int i2 = -1;
#pragma unroll
    for (int e = 0; e < NR; ++e) {
      if (e == i1) continue;
      if (i2 < 0 || sel[e] > sel[i2]) i2 = e;
    }
    float c[NR] = {0.f, 0.f, 0.f, 0.f, 0.f, 0.f, 0.f};
    c[i1] = pr[i1];
    c[i2] += pr[i2];
#pragma unroll
    for (int e = 0; e < NR; ++e) cw[(size_t)wid * NR + e] = c[e];
    atomicAdd(&cnt[i1], 1);
    atomicAdd(&cnt[i2], 1);
  }
}

// ---------------- scan: offsets + compact tile map ----------------
__global__ void scan_kernel(const int* __restrict__ cnt, int* __restrict__ offs,
                            int* __restrict__ tmap, int* __restrict__ ntiles) {
  int o = 0, nt = 0;
  for (int e = 0; e < NR; ++e) {
    offs[e] = o;
    int n = (cnt[e] + 127) & ~127;
    o += n;
    for (int tm = 0; tm < n; tm += 128) tmap[nt++] = (e << 16) | tm;
  }
  *ntiles = nt;
}

// ---------------- place: fill gathered index lists + per-token slot/weight ----------------
__global__ __launch_bounds__(256) void place_kernel(const float* __restrict__ cw,
                                                    const int* __restrict__ offs,
                                                    int* __restrict__ cursor,
                                                    int* __restrict__ idx,
                                                    int* __restrict__ tok2slot,
                                                    float* __restrict__ tok2w) {
  int t = blockIdx.x * 256 + threadIdx.x;
  if (t >= NTOK) return;
  int k = 0;
#pragma unroll
  for (int e = 0; e < NR; ++e) {
    float w = cw[(size_t)t * NR + e];
    if (w > 0.f) {
      int p = atomicAdd(&cursor[e], 1);
      int slot = offs[e] + p;
      idx[slot] = t;
      tok2slot[t * 2 + k] = slot;
      tok2w[t * 2 + k] = w;
      ++k;
    }
  }
}

// ---------------- transpose + cast all 8 experts: fp32 [R][S] -> bf16 [S][R] ----------------
__global__ void transpose_cast_all(const float* __restrict__ shared_w,
                                   const float* __restrict__ routed_w,
                                   unsigned short* __restrict__ out, int R, int S) {
  int e = blockIdx.z;
  const float* in = (e == 0) ? shared_w : routed_w + (size_t)(e - 1) * R * S;
  unsigned short* o = out + (size_t)e * R * S;
  __shared__ float t[32][33];
  int bx = blockIdx.x * 32;  // S
  int by = blockIdx.y * 32;  // R
  int tx = threadIdx.x, ty = threadIdx.y;  // (32, 8)
#pragma unroll
  for (int i = 0; i < 32; i += 8)
    t[ty + i][tx] = in[(size_t)(by + ty + i) * S + bx + tx];
  __syncthreads();
#pragma unroll
  for (int i = 0; i < 32; i += 8)
    o[(size_t)(bx + ty + i) * R + by + tx] = f2bf(t[tx][ty + i]);
}

// ---------------- fc GEMM (2-phase dbuf): A rows x wfcT -> gelu -> Y (bf16) ----------------
template <bool GATHER>
__global__ __launch_bounds__(256) void gemm_fc(const unsigned short* __restrict__ A,
                                               const unsigned short* __restrict__ BtAll,
                                               unsigned short* __restrict__ Y,
                                               const int* __restrict__ idx,
                                               const int* __restrict__ offs,
                                               const int* __restrict__ tmap,
                                               const int* __restrict__ ntiles) {
  __shared__ __align__(16) unsigned short As[2][4096];
  __shared__ __align__(16) unsigned short Bs[2][4096];
  const int tid = threadIdx.x;
  const int wave = tid >> 6, lane = tid & 63;

  int m0, n0, base;
  const unsigned short* Bt;
  if (GATHER) {
    if (blockIdx.y >= *ntiles) return;
    const int packed = tmap[blockIdx.y];
    const int e = packed >> 16;
    m0 = packed & 0xffff;
    n0 = blockIdx.x * 128;
    base = offs[e];
    Bt = BtAll + (size_t)(e + 1) * WSZ;
  } else {
    const int f = blockIdx.y * gridDim.x + blockIdx.x;
    const int cpx = (gridDim.x * gridDim.y) >> 3;
    const int swz = (f & 7) * cpx + (f >> 3);
    m0 = (swz / gridDim.x) * 128;
    n0 = (swz % gridDim.x) * 128;
    base = 0;
    Bt = BtAll;
  }

  const int q0 = wave * 128 + lane, q1 = q0 + 64;
  const int kg0 = q0 >> 7, r0 = q0 & 127;
  const int kg1 = q1 >> 7, r1 = q1 & 127;
  const size_t rowA0 = GATHER ? (size_t)idx[base + m0 + r0] : (size_t)(m0 + r0);
  const size_t rowA1 = GATHER ? (size_t)idx[base + m0 + r1] : (size_t)(m0 + r1);
  const unsigned short* gA0 = A + rowA0 * C_DIM + kg0 * 8;
  const unsigned short* gA1 = A + rowA1 * C_DIM + kg1 * 8;
  const unsigned short* gB0 = Bt + (size_t)(n0 + r0) * C_DIM + kg0 * 8;
  const unsigned short* gB1 = Bt + (size_t)(n0 + r1) * C_DIM + kg1 * 8;
  const int c0 = (wave * 2 + 0) * 512, c1 = (wave * 2 + 1) * 512;

  const int wr = wave >> 1, wc = wave & 1;
  const int fr = lane & 15, fq = lane >> 4;
  f32x4 acc[4][4] = {};

  // prologue: stage k=0 into buf 0
  gload16(gA0, &As[0][c0]);
  gload16(gA1, &As[0][c1]);
  gload16(gB0, &Bs[0][c0]);
  gload16(gB1, &Bs[0][c1]);

  int buf = 0;
  for (int k0 = 0; k0 < C_DIM; k0 += 32) {
    __syncthreads();  // vmcnt(0) drain: buf `buf` is ready
    const int nk = k0 + 32;
    if (nk < C_DIM) {
      const int nb = buf ^ 1;  // stage next tile while computing current
      gload16(gA0 + nk, &As[nb][c0]);
      gload16(gA1 + nk, &As[nb][c1]);
      gload16(gB0 + nk, &Bs[nb][c0]);
      gload16(gB1 + nk, &Bs[nb][c1]);
    }
    bf16x8 af[4], bfr[4];
#pragma unroll
    for (int m = 0; m < 4; ++m)
      af[m] = *(const bf16x8*)&As[buf][fq * 1024 + (wr * 64 + m * 16 + fr) * 8];
#pragma unroll
    for (int n = 0; n < 4; ++n)
      bfr[n] = *(const bf16x8*)&Bs[buf][fq * 1024 + (wc * 64 + n * 16 + fr) * 8];
#pragma unroll
    for (int m = 0; m < 4; ++m)
#pragma unroll
      for (int n = 0; n < 4; ++n)
        acc[m][n] = __builtin_amdgcn_mfma_f32_16x16x32_bf16(af[m], bfr[n], acc[m][n], 0, 0, 0);
    buf ^= 1;
  }

#pragma unroll
  for (int m = 0; m < 4; ++m)
#pragma unroll
    for (int n = 0; n < 4; ++n)
#pragma unroll
      for (int j = 0; j < 4; ++j) {
        const int row = m0 + wr * 64 + m * 16 + fq * 4 + j;
        const int col = n0 + wc * 64 + n * 16 + fr;
        const float v = acc[m][n][j];
        const float g = 0.5f * v * (1.0f + erff(v * 0.70710678118654752f));
        Y[(size_t)(base + row) * H_DIM + col] = f2bf(g);
      }
}

// ---------------- proj GEMM (2-phase dbuf): Y x wprojT ----------------
// ROUTED: plain store raw v into Yout[slot][C]   else: out[row] = v (shared)
template <bool ROUTED>
__global__ __launch_bounds__(256) void gemm_proj(const unsigned short* __restrict__ Yg,
                                                 const unsigned short* __restrict__ BtAll,
                                                 float* __restrict__ Out,
                                                 const int* __restrict__ offs,
                                                 const int* __restrict__ tmap,
                                                 const int* __restrict__ ntiles) {
  __shared__ __align__(16) unsigned short As[2][4096];
  __shared__ __align__(16) unsigned short Bs[2][4096];
  const int tid = threadIdx.x;
  const int wave = tid >> 6, lane = tid & 63;

  int m0, n0, base;
  const unsigned short* Bt;
  if (ROUTED) {
    if (blockIdx.y >= *ntiles) return;
    const int packed = tmap[blockIdx.y];
    const int e = packed >> 16;
    m0 = packed & 0xffff;
    n0 = blockIdx.x * 128;
    base = offs[e];
    Bt = BtAll + (size_t)(e + 1) * WSZ;
  } else {
    const int f = blockIdx.y * gridDim.x + blockIdx.x;
    const int cpx = (gridDim.x * gridDim.y) >> 3;
    const int swz = (f & 7) * cpx + (f >> 3);
    m0 = (swz / gridDim.x) * 128;
    n0 = (swz % gridDim.x) * 128;
    base = 0;
    Bt = BtAll;
  }

  const int q0 = wave * 128 + lane, q1 = q0 + 64;
  const int kg0 = q0 >> 7, r0 = q0 & 127;
  const int kg1 = q1 >> 7, r1 = q1 & 127;
  const unsigned short* gA0 = Yg + (size_t)(base + m0 + r0) * H_DIM + kg0 * 8;
  const unsigned short* gA1 = Yg + (size_t)(base + m0 + r1) * H_DIM + kg1 * 8;
  const unsigned short* gB0 = Bt + (size_t)(n0 + r0) * H_DIM + kg0 * 8;
  const unsigned short* gB1 = Bt + (size_t)(n0 + r1) * H_DIM + kg1 * 8;
  const int c0 = (wave * 2 + 0) * 512, c1 = (wave * 2 + 1) * 512;

  const int wr = wave >> 1, wc = wave & 1;
  const int fr = lane & 15, fq = lane >> 4;
  f32x4 acc[4][4] = {};

  gload16(gA0, &As[0][c0]);
  gload16(gA1, &As[0][c1]);
  gload16(gB0, &Bs[0][c0]);
  gload16(gB1, &Bs[0][c1]);

  int buf = 0;
  for (int k0 = 0; k0 < H_DIM; k0 += 32) {
    __syncthreads();
    const int nk = k0 + 32;
    if (nk < H_DIM) {
      const int nb = buf ^ 1;
      gload16(gA0 + nk, &As[nb][c0]);
      gload16(gA1 + nk, &As[nb][c1]);
      gload16(gB0 + nk, &Bs[nb][c0]);
      gload16(gB1 + nk, &Bs[nb][c1]);
    }
    bf16x8 af[4], bfr[4];
#pragma unroll
    for (int m = 0; m < 4; ++m)
      af[m] = *(const bf16x8*)&As[buf][fq * 1024 + (wr * 64 + m * 16 + fr) * 8];
#pragma unroll
    for (int n = 0; n < 4; ++n)
      bfr[n] = *(const bf16x8*)&Bs[buf][fq * 1024 + (wc * 64 + n * 16 + fr) * 8];
#pragma unroll
    for (int m = 0; m < 4; ++m)
#pragma unroll
      for (int n = 0; n < 4; ++n)
        acc[m][n] = __builtin_amdgcn_mfma_f32_16x16x32_bf16(af[m], bfr[n], acc[m][n], 0, 0, 0);
    buf ^= 1;
  }

#pragma unroll
  for (int m = 0; m < 4; ++m)
#pragma unroll
    for (int n = 0; n < 4; ++n)
#pragma unroll
      for (int j = 0; j < 4; ++j) {
        const int p = wr * 64 + m * 16 + fq * 4 + j;
        const int col = n0 + wc * 64 + n * 16 + fr;
        const float v = acc[m][n][j];
        // ROUTED: Out == Yout (per-slot buffer); else Out == d_out (row == token)
        Out[(size_t)(base + m0 + p) * C_DIM + col] = v;
      }
}

// ---------------- combine: out[t] += w0*Yout[slot0] + w1*Yout[slot1] ----------------
__global__ __launch_bounds__(256) void combine_kernel(const float* __restrict__ Yout,
                                                      const int* __restrict__ tok2slot,
                                                      const float* __restrict__ tok2w,
                                                      float* __restrict__ out) {
  const int t = blockIdx.x;          // one block per token (C=1024 = 256 float4)
  const int c4 = threadIdx.x;
  const int s0 = tok2slot[t * 2], s1 = tok2slot[t * 2 + 1];
  const float w0 = tok2w[t * 2], w1 = tok2w[t * 2 + 1];
  const float4 a = ((const float4*)(Yout + (size_t)s0 * C_DIM))[c4];
  const float4 b = ((const float4*)(Yout + (size_t)s1 * C_DIM))[c4];
  float4 o = ((float4*)(out + (size_t)t * C_DIM))[c4];
  o.x += w0 * a.x + w1 * b.x;
  o.y += w0 * a.y + w1 * b.y;
  o.z += w0 * a.z + w1 * b.z;
  o.w += w0 * a.w + w1 * b.w;
  ((float4*)(out + (size_t)t * C_DIM))[c4] = o;
}

extern "C" void kernel_launch(void* const* d_in, const int* in_sizes, int n_in,
                              void* d_out, int out_size, void* d_ws, size_t ws_size,
                              hipStream_t stream) {
  const float* x            = (const float*)d_in[0];
  const float* gate_w       = (const float*)d_in[1];
  const float* lb_bias      = (const float*)d_in[2];
  const float* shared_wfc   = (const float*)d_in[3];
  const float* shared_wproj = (const float*)d_in[4];
  const float* routed_wfc   = (const float*)d_in[5];
  const float* routed_wproj = (const float*)d_in[6];
  float* out = (float*)d_out;

  char* ws = (char*)d_ws;
  unsigned short* xb     = (unsigned short*)(ws);                 // 16 MiB (dead after routed fc)
  unsigned short* wfcT   = (unsigned short*)(ws + 16777216);      // 64 MiB (dead after routed fc)
  float*          Yout   = (float*)(ws);                          // 68 MiB, OVERLAYS xb+wfcT (80 MiB)
  unsigned short* wprojT = (unsigned short*)(ws + 83886080);      // 64 MiB [8][C][H]
  unsigned short* Yg     = (unsigned short*)(ws + 150994944);     // 136 MiB [MAXG][H]
  float*          cw     = (float*)(ws + 293601280);              // 224 KiB
  int*            idx    = (int*)(ws + 293830656);                // 68 KiB
  int*            cnt    = (int*)(ws + 293900288);
  int*            offs   = (int*)(ws + 293900352);
  int*            cursor = (int*)(ws + 293900416);
  int*            tok2slot = (int*)(ws + 293900480);              // 64 KiB
  float*          tok2w    = (float*)(ws + 293966016);            // 64 KiB
  int*            tmap     = (int*)(ws + 294031552);              // 544 B
  int*            ntiles   = (int*)(ws + 294032128);

  cast_x_kernel<<<NTOK * C_DIM / (256 * 4), 256, 0, stream>>>(x, xb);
  init_kernel<<<(MAXG + 255) / 256, 256, 0, stream>>>(idx, cnt, cursor);
  routing_kernel<<<NTOK / 4, 256, 0, stream>>>(x, gate_w, lb_bias, cw, cnt);
  scan_kernel<<<1, 1, 0, stream>>>(cnt, offs, tmap, ntiles);
  place_kernel<<<NTOK / 256, 256, 0, stream>>>(cw, offs, cursor, idx, tok2slot, tok2w);

  // all-expert weight transposes (e=0 shared, e=1..7 routed)
  transpose_cast_all<<<dim3(H_DIM / 32, C_DIM / 32, 8), dim3(32, 8), 0, stream>>>(
      shared_wfc, routed_wfc, wfcT, C_DIM, H_DIM);
  transpose_cast_all<<<dim3(C_DIM / 32, H_DIM / 32, 8), dim3(32, 8), 0, stream>>>(
      shared_wproj, routed_wproj, wprojT, H_DIM, C_DIM);

  // shared expert (dense): fc -> Yg[0:8192), proj -> out (plain store)
  gemm_fc<false><<<dim3(H_DIM / 128, NTOK / 128), 256, 0, stream>>>(
      xb, wfcT, Yg, idx, offs, tmap, ntiles);
  gemm_proj<false><<<dim3(C_DIM / 128, NTOK / 128), 256, 0, stream>>>(
      Yg, wprojT, out, offs, tmap, ntiles);

  // routed experts (gathered, top-2): compact tile grid, every block live
  gemm_fc<true><<<dim3(H_DIM / 128, MAXT), 256, 0, stream>>>(
      xb, wfcT, Yg, idx, offs, tmap, ntiles);
  gemm_proj<true><<<dim3(C_DIM / 128, MAXT), 256, 0, stream>>>(
      Yg, wprojT, Yout, offs, tmap, ntiles);

  // out[t] += w0*Yout[slot0] + w1*Yout[slot1]
  combine_kernel<<<NTOK, 256, 0, stream>>>(Yout, tok2slot, tok2w, out);
}

// Round 6
// 1282.281 us; speedup vs baseline: 2.0791x; 1.0436x over previous
//
#include <hip/hip_runtime.h>
#include <hip/hip_bf16.h>

#define AS1 __attribute__((address_space(1)))
#define AS3 __attribute__((address_space(3)))

typedef __bf16 bf16x8 __attribute__((ext_vector_type(8)));
typedef float f32x4 __attribute__((ext_vector_type(4)));

static constexpr int C_DIM = 1024;
static constexpr int H_DIM = 4096;
static constexpr int NTOK  = 8192;   // 4*2048
static constexpr int NR    = 7;      // routed experts
static constexpr int MAXG  = 17408;  // gathered-row capacity (>= 135*128)
static constexpr int MAXT  = 136;    // max m-tiles across routed experts
static constexpr size_t WSZ = (size_t)C_DIM * H_DIM;  // elems per expert weight

static __device__ __forceinline__ unsigned short f2bf(float f) {
  __hip_bfloat16 h = __float2bfloat16(f);
  return *reinterpret_cast<unsigned short*>(&h);
}

static __device__ __forceinline__ void gload16(const void* g, void* lds) {
  __builtin_amdgcn_global_load_lds((const AS1 void*)g, (AS3 void*)lds, 16, 0, 0);
}

// ---------------- cast x (fp32 -> bf16) ----------------
__global__ __launch_bounds__(256) void cast_x_kernel(const float* __restrict__ x,
                                                     unsigned short* __restrict__ xb) {
  size_t i = ((size_t)blockIdx.x * blockDim.x + threadIdx.x) * 4;
  float4 v = *(const float4*)(x + i);
  ushort4 o;
  o.x = f2bf(v.x); o.y = f2bf(v.y); o.z = f2bf(v.z); o.w = f2bf(v.w);
  *(ushort4*)(xb + i) = o;
}

// ---------------- init: zero idx / cnt / cursor ----------------
__global__ __launch_bounds__(256) void init_kernel(int* __restrict__ idx, int* __restrict__ cnt,
                                                   int* __restrict__ cursor) {
  int i = blockIdx.x * 256 + threadIdx.x;
  if (i < MAXG) idx[i] = 0;
  if (blockIdx.x == 0 && threadIdx.x < 8) { cnt[threadIdx.x] = 0; cursor[threadIdx.x] = 0; }
}

// ---------------- routing: one wave per token; writes cw + counts ----------------
__global__ __launch_bounds__(256) void routing_kernel(const float* __restrict__ x,
                                                      const float* __restrict__ gw,
                                                      const float* __restrict__ bias,
                                                      float* __restrict__ cw,
                                                      int* __restrict__ cnt) {
  int wid = (int)((blockIdx.x * (size_t)blockDim.x + threadIdx.x) >> 6);
  int lane = threadIdx.x & 63;
  if (wid >= NTOK) return;
  const float* xt = x + (size_t)wid * C_DIM;
  float p[NR] = {0.f, 0.f, 0.f, 0.f, 0.f, 0.f, 0.f};
  for (int i = lane; i < C_DIM; i += 64) {
    float xv = xt[i];
#pragma unroll
    for (int e = 0; e < NR; ++e) p[e] += xv * gw[e * C_DIM + i];
  }
#pragma unroll
  for (int e = 0; e < NR; ++e) {
#pragma unroll
    for (int off = 32; off; off >>= 1) p[e] += __shfl_down(p[e], off);
  }
  if (lane == 0) {
    float m = p[0];
#pragma unroll
    for (int e = 1; e < NR; ++e) m = fmaxf(m, p[e]);
    float pr[NR], s = 0.f;
#pragma unroll
    for (int e = 0; e < NR; ++e) { pr[e] = __expf(p[e] - m); s += pr[e]; }
    float inv = 1.0f / s;
#pragma unroll
    for (int e = 0; e < NR; ++e) pr[e] *= inv;
    float sel[NR];
#pragma unroll
    for (int e = 0; e < NR; ++e) sel[e] = p[e] + bias[e];
    int i1 = 0;
#pragma unroll
    for (int e = 1; e < NR; ++e) if (sel[e] > sel[i1]) i1 = e;
    int i2 = -1;
#pragma unroll
    for (int e = 0; e < NR; ++e) {
      if (e == i1) continue;
      if (i2 < 0 || sel[e] > sel[i2]) i2 = e;
    }
    float c[NR] = {0.f, 0.f, 0.f, 0.f, 0.f, 0.f, 0.f};
    c[i1] = pr[i1];
    c[i2] += pr[i2];
#pragma unroll
    for (int e = 0; e < NR; ++e) cw[(size_t)wid * NR + e] = c[e];
    atomicAdd(&cnt[i1], 1);
    atomicAdd(&cnt[i2], 1);
  }
}

// ---------------- scan: offsets + compact tile map ----------------
__global__ void scan_kernel(const int* __restrict__ cnt, int* __restrict__ offs,
                            int* __restrict__ tmap, int* __restrict__ ntiles) {
  int o = 0, nt = 0;
  for (int e = 0; e < NR; ++e) {
    offs[e] = o;
    int n = (cnt[e] + 127) & ~127;
    o += n;
    for (int tm = 0; tm < n; tm += 128) tmap[nt++] = (e << 16) | tm;
  }
  *ntiles = nt;
}

// ---------------- place: fill gathered index lists + per-token slot/weight ----------------
__global__ __launch_bounds__(256) void place_kernel(const float* __restrict__ cw,
                                                    const int* __restrict__ offs,
                                                    int* __restrict__ cursor,
                                                    int* __restrict__ idx,
                                                    int* __restrict__ tok2slot,
                                                    float* __restrict__ tok2w) {
  int t = blockIdx.x * 256 + threadIdx.x;
  if (t >= NTOK) return;
  int k = 0;
#pragma unroll
  for (int e = 0; e < NR; ++e) {
    float w = cw[(size_t)t * NR + e];
    if (w > 0.f) {
      int p = atomicAdd(&cursor[e], 1);
      int slot = offs[e] + p;
      idx[slot] = t;
      tok2slot[t * 2 + k] = slot;
      tok2w[t * 2 + k] = w;
      ++k;
    }
  }
}

// ---------------- transpose + cast all 8 experts: fp32 [R][S] -> bf16 [S][R] ----------------
__global__ void transpose_cast_all(const float* __restrict__ shared_w,
                                   const float* __restrict__ routed_w,
                                   unsigned short* __restrict__ out, int R, int S) {
  int e = blockIdx.z;
  const float* in = (e == 0) ? shared_w : routed_w + (size_t)(e - 1) * R * S;
  unsigned short* o = out + (size_t)e * R * S;
  __shared__ float t[32][33];
  int bx = blockIdx.x * 32;  // S
  int by = blockIdx.y * 32;  // R
  int tx = threadIdx.x, ty = threadIdx.y;  // (32, 8)
#pragma unroll
  for (int i = 0; i < 32; i += 8)
    t[ty + i][tx] = in[(size_t)(by + ty + i) * S + bx + tx];
  __syncthreads();
#pragma unroll
  for (int i = 0; i < 32; i += 8)
    o[(size_t)(bx + ty + i) * R + by + tx] = f2bf(t[tx][ty + i]);
}

// ======== GEMM K-loop core: 3-buffer depth-2 pipeline, counted vmcnt ========
// Invariants (see analysis): writer of buf b targets the buffer read 3 tiles
// earlier, protected by the trailing barrier; tile-t reads protected by own
// vmcnt + leading barrier. vmcnt never drains to 0 in the main loop (T4).

// ---------------- fc GEMM: A rows x wfcT -> gelu -> Y (bf16) ----------------
template <bool GATHER>
__global__ __launch_bounds__(256) void gemm_fc(const unsigned short* __restrict__ A,
                                               const unsigned short* __restrict__ BtAll,
                                               unsigned short* __restrict__ Y,
                                               const int* __restrict__ idx,
                                               const int* __restrict__ offs,
                                               const int* __restrict__ tmap,
                                               const int* __restrict__ ntiles) {
  __shared__ __align__(16) unsigned short As[3][4096];
  __shared__ __align__(16) unsigned short Bs[3][4096];
  const int tid = threadIdx.x;
  const int wave = tid >> 6, lane = tid & 63;
  constexpr int NT = C_DIM / 32;

  int m0, n0, base;
  const unsigned short* Bt;
  if (GATHER) {
    if (blockIdx.y >= *ntiles) return;
    const int packed = tmap[blockIdx.y];
    const int e = packed >> 16;
    m0 = packed & 0xffff;
    n0 = blockIdx.x * 128;
    base = offs[e];
    Bt = BtAll + (size_t)(e + 1) * WSZ;
  } else {
    const int f = blockIdx.y * gridDim.x + blockIdx.x;
    const int cpx = (gridDim.x * gridDim.y) >> 3;
    const int swz = (f & 7) * cpx + (f >> 3);
    m0 = (swz / gridDim.x) * 128;
    n0 = (swz % gridDim.x) * 128;
    base = 0;
    Bt = BtAll;
  }

  const int q0 = wave * 128 + lane, q1 = q0 + 64;
  const int kg0 = q0 >> 7, r0 = q0 & 127;
  const int kg1 = q1 >> 7, r1 = q1 & 127;
  const size_t rowA0 = GATHER ? (size_t)idx[base + m0 + r0] : (size_t)(m0 + r0);
  const size_t rowA1 = GATHER ? (size_t)idx[base + m0 + r1] : (size_t)(m0 + r1);
  const unsigned short* gA0 = A + rowA0 * C_DIM + kg0 * 8;
  const unsigned short* gA1 = A + rowA1 * C_DIM + kg1 * 8;
  const unsigned short* gB0 = Bt + (size_t)(n0 + r0) * C_DIM + kg0 * 8;
  const unsigned short* gB1 = Bt + (size_t)(n0 + r1) * C_DIM + kg1 * 8;
  const int c0 = (wave * 2 + 0) * 512, c1 = (wave * 2 + 1) * 512;

  const int wr = wave >> 1, wc = wave & 1;
  const int fr = lane & 15, fq = lane >> 4;
  f32x4 acc[4][4] = {};

  asm volatile("s_waitcnt vmcnt(0)" ::: "memory");  // idx loads retired
  // prologue: stage tiles 0,1 into bufs 0,1
  gload16(gA0, &As[0][c0]); gload16(gA1, &As[0][c1]);
  gload16(gB0, &Bs[0][c0]); gload16(gB1, &Bs[0][c1]);
  gload16(gA0 + 32, &As[1][c0]); gload16(gA1 + 32, &As[1][c1]);
  gload16(gB0 + 32, &Bs[1][c0]); gload16(gB1 + 32, &Bs[1][c1]);

  int rb = 0;
  for (int t = 0; t < NT; ++t) {
    if (t + 2 < NT) {
      const int wb = (rb >= 1) ? rb - 1 : rb + 2;  // (rb+2)%3
      const int nk = (t + 2) * 32;
      gload16(gA0 + nk, &As[wb][c0]); gload16(gA1 + nk, &As[wb][c1]);
      gload16(gB0 + nk, &Bs[wb][c0]); gload16(gB1 + nk, &Bs[wb][c1]);
      asm volatile("s_waitcnt vmcnt(8)" ::: "memory");
    } else if (t + 1 < NT) {
      asm volatile("s_waitcnt vmcnt(4)" ::: "memory");
    } else {
      asm volatile("s_waitcnt vmcnt(0)" ::: "memory");
    }
    __builtin_amdgcn_s_barrier();  // all waves' tile-t loads landed in LDS
    bf16x8 af[4], bfr[4];
#pragma unroll
    for (int m = 0; m < 4; ++m)
      af[m] = *(const bf16x8*)&As[rb][fq * 1024 + (wr * 64 + m * 16 + fr) * 8];
#pragma unroll
    for (int n = 0; n < 4; ++n)
      bfr[n] = *(const bf16x8*)&Bs[rb][fq * 1024 + (wc * 64 + n * 16 + fr) * 8];
#pragma unroll
    for (int m = 0; m < 4; ++m)
#pragma unroll
      for (int n = 0; n < 4; ++n)
        acc[m][n] = __builtin_amdgcn_mfma_f32_16x16x32_bf16(af[m], bfr[n], acc[m][n], 0, 0, 0);
    __builtin_amdgcn_s_barrier();  // all waves done reading buf rb (reused at t+1's stage)
    rb = (rb == 2) ? 0 : rb + 1;
  }

#pragma unroll
  for (int m = 0; m < 4; ++m)
#pragma unroll
    for (int n = 0; n < 4; ++n)
#pragma unroll
      for (int j = 0; j < 4; ++j) {
        const int row = m0 + wr * 64 + m * 16 + fq * 4 + j;
        const int col = n0 + wc * 64 + n * 16 + fr;
        const float v = acc[m][n][j];
        const float g = 0.5f * v * (1.0f + erff(v * 0.70710678118654752f));
        Y[(size_t)(base + row) * H_DIM + col] = f2bf(g);
      }
}

// ---------------- proj GEMM: Y x wprojT ----------------
// ROUTED: plain store raw v into Yout[slot][C]   else: out[row] = v (shared)
template <bool ROUTED>
__global__ __launch_bounds__(256) void gemm_proj(const unsigned short* __restrict__ Yg,
                                                 const unsigned short* __restrict__ BtAll,
                                                 float* __restrict__ Out,
                                                 const int* __restrict__ offs,
                                                 const int* __restrict__ tmap,
                                                 const int* __restrict__ ntiles) {
  __shared__ __align__(16) unsigned short As[3][4096];
  __shared__ __align__(16) unsigned short Bs[3][4096];
  const int tid = threadIdx.x;
  const int wave = tid >> 6, lane = tid & 63;
  constexpr int NT = H_DIM / 32;

  int m0, n0, base;
  const unsigned short* Bt;
  if (ROUTED) {
    if (blockIdx.y >= *ntiles) return;
    const int packed = tmap[blockIdx.y];
    const int e = packed >> 16;
    m0 = packed & 0xffff;
    n0 = blockIdx.x * 128;
    base = offs[e];
    Bt = BtAll + (size_t)(e + 1) * WSZ;
  } else {
    const int f = blockIdx.y * gridDim.x + blockIdx.x;
    const int cpx = (gridDim.x * gridDim.y) >> 3;
    const int swz = (f & 7) * cpx + (f >> 3);
    m0 = (swz / gridDim.x) * 128;
    n0 = (swz % gridDim.x) * 128;
    base = 0;
    Bt = BtAll;
  }

  const int q0 = wave * 128 + lane, q1 = q0 + 64;
  const int kg0 = q0 >> 7, r0 = q0 & 127;
  const int kg1 = q1 >> 7, r1 = q1 & 127;
  const unsigned short* gA0 = Yg + (size_t)(base + m0 + r0) * H_DIM + kg0 * 8;
  const unsigned short* gA1 = Yg + (size_t)(base + m0 + r1) * H_DIM + kg1 * 8;
  const unsigned short* gB0 = Bt + (size_t)(n0 + r0) * H_DIM + kg0 * 8;
  const unsigned short* gB1 = Bt + (size_t)(n0 + r1) * H_DIM + kg1 * 8;
  const int c0 = (wave * 2 + 0) * 512, c1 = (wave * 2 + 1) * 512;

  const int wr = wave >> 1, wc = wave & 1;
  const int fr = lane & 15, fq = lane >> 4;
  f32x4 acc[4][4] = {};

  asm volatile("s_waitcnt vmcnt(0)" ::: "memory");
  gload16(gA0, &As[0][c0]); gload16(gA1, &As[0][c1]);
  gload16(gB0, &Bs[0][c0]); gload16(gB1, &Bs[0][c1]);
  gload16(gA0 + 32, &As[1][c0]); gload16(gA1 + 32, &As[1][c1]);
  gload16(gB0 + 32, &Bs[1][c0]); gload16(gB1 + 32, &Bs[1][c1]);

  int rb = 0;
  for (int t = 0; t < NT; ++t) {
    if (t + 2 < NT) {
      const int wb = (rb >= 1) ? rb - 1 : rb + 2;  // (rb+2)%3
      const int nk = (t + 2) * 32;
      gload16(gA0 + nk, &As[wb][c0]); gload16(gA1 + nk, &As[wb][c1]);
      gload16(gB0 + nk, &Bs[wb][c0]); gload16(gB1 + nk, &Bs[wb][c1]);
      asm volatile("s_waitcnt vmcnt(8)" ::: "memory");
    } else if (t + 1 < NT) {
      asm volatile("s_waitcnt vmcnt(4)" ::: "memory");
    } else {
      asm volatile("s_waitcnt vmcnt(0)" ::: "memory");
    }
    __builtin_amdgcn_s_barrier();
    bf16x8 af[4], bfr[4];
#pragma unroll
    for (int m = 0; m < 4; ++m)
      af[m] = *(const bf16x8*)&As[rb][fq * 1024 + (wr * 64 + m * 16 + fr) * 8];
#pragma unroll
    for (int n = 0; n < 4; ++n)
      bfr[n] = *(const bf16x8*)&Bs[rb][fq * 1024 + (wc * 64 + n * 16 + fr) * 8];
#pragma unroll
    for (int m = 0; m < 4; ++m)
#pragma unroll
      for (int n = 0; n < 4; ++n)
        acc[m][n] = __builtin_amdgcn_mfma_f32_16x16x32_bf16(af[m], bfr[n], acc[m][n], 0, 0, 0);
    __builtin_amdgcn_s_barrier();
    rb = (rb == 2) ? 0 : rb + 1;
  }

#pragma unroll
  for (int m = 0; m < 4; ++m)
#pragma unroll
    for (int n = 0; n < 4; ++n)
#pragma unroll
      for (int j = 0; j < 4; ++j) {
        const int p = wr * 64 + m * 16 + fq * 4 + j;
        const int col = n0 + wc * 64 + n * 16 + fr;
        const float v = acc[m][n][j];
        // ROUTED: Out == Yout (per-slot buffer); else Out == d_out (row == token)
        Out[(size_t)(base + m0 + p) * C_DIM + col] = v;
      }
}

// ---------------- combine: out[t] += w0*Yout[slot0] + w1*Yout[slot1] ----------------
__global__ __launch_bounds__(256) void combine_kernel(const float* __restrict__ Yout,
                                                      const int* __restrict__ tok2slot,
                                                      const float* __restrict__ tok2w,
                                                      float* __restrict__ out) {
  const int t = blockIdx.x;          // one block per token (C=1024 = 256 float4)
  const int c4 = threadIdx.x;
  const int s0 = tok2slot[t * 2], s1 = tok2slot[t * 2 + 1];
  const float w0 = tok2w[t * 2], w1 = tok2w[t * 2 + 1];
  const float4 a = ((const float4*)(Yout + (size_t)s0 * C_DIM))[c4];
  const float4 b = ((const float4*)(Yout + (size_t)s1 * C_DIM))[c4];
  float4 o = ((float4*)(out + (size_t)t * C_DIM))[c4];
  o.x += w0 * a.x + w1 * b.x;
  o.y += w0 * a.y + w1 * b.y;
  o.z += w0 * a.z + w1 * b.z;
  o.w += w0 * a.w + w1 * b.w;
  ((float4*)(out + (size_t)t * C_DIM))[c4] = o;
}

extern "C" void kernel_launch(void* const* d_in, const int* in_sizes, int n_in,
                              void* d_out, int out_size, void* d_ws, size_t ws_size,
                              hipStream_t stream) {
  const float* x            = (const float*)d_in[0];
  const float* gate_w       = (const float*)d_in[1];
  const float* lb_bias      = (const float*)d_in[2];
  const float* shared_wfc   = (const float*)d_in[3];
  const float* shared_wproj = (const float*)d_in[4];
  const float* routed_wfc   = (const float*)d_in[5];
  const float* routed_wproj = (const float*)d_in[6];
  float* out = (float*)d_out;

  char* ws = (char*)d_ws;
  unsigned short* xb     = (unsigned short*)(ws);                 // 16 MiB (dead after routed fc)
  unsigned short* wfcT   = (unsigned short*)(ws + 16777216);      // 64 MiB (dead after routed fc)
  float*          Yout   = (float*)(ws);                          // 68 MiB, OVERLAYS xb+wfcT (80 MiB)
  unsigned short* wprojT = (unsigned short*)(ws + 83886080);      // 64 MiB [8][C][H]
  unsigned short* Yg     = (unsigned short*)(ws + 150994944);     // 136 MiB [MAXG][H]
  float*          cw     = (float*)(ws + 293601280);              // 224 KiB
  int*            idx    = (int*)(ws + 293830656);                // 68 KiB
  int*            cnt    = (int*)(ws + 293900288);
  int*            offs   = (int*)(ws + 293900352);
  int*            cursor = (int*)(ws + 293900416);
  int*            tok2slot = (int*)(ws + 293900480);              // 64 KiB
  float*          tok2w    = (float*)(ws + 293966016);            // 64 KiB
  int*            tmap     = (int*)(ws + 294031552);              // 544 B
  int*            ntiles   = (int*)(ws + 294032128);

  cast_x_kernel<<<NTOK * C_DIM / (256 * 4), 256, 0, stream>>>(x, xb);
  init_kernel<<<(MAXG + 255) / 256, 256, 0, stream>>>(idx, cnt, cursor);
  routing_kernel<<<NTOK / 4, 256, 0, stream>>>(x, gate_w, lb_bias, cw, cnt);
  scan_kernel<<<1, 1, 0, stream>>>(cnt, offs, tmap, ntiles);
  place_kernel<<<NTOK / 256, 256, 0, stream>>>(cw, offs, cursor, idx, tok2slot, tok2w);

  // all-expert weight transposes (e=0 shared, e=1..7 routed)
  transpose_cast_all<<<dim3(H_DIM / 32, C_DIM / 32, 8), dim3(32, 8), 0, stream>>>(
      shared_wfc, routed_wfc, wfcT, C_DIM, H_DIM);
  transpose_cast_all<<<dim3(C_DIM / 32, H_DIM / 32, 8), dim3(32, 8), 0, stream>>>(
      shared_wproj, routed_wproj, wprojT, H_DIM, C_DIM);

  // shared expert (dense): fc -> Yg[0:8192), proj -> out (plain store)
  gemm_fc<false><<<dim3(H_DIM / 128, NTOK / 128), 256, 0, stream>>>(
      xb, wfcT, Yg, idx, offs, tmap, ntiles);
  gemm_proj<false><<<dim3(C_DIM / 128, NTOK / 128), 256, 0, stream>>>(
      Yg, wprojT, out, offs, tmap, ntiles);

  // routed experts (gathered, top-2): compact tile grid, every block live
  gemm_fc<true><<<dim3(H_DIM / 128, MAXT), 256, 0, stream>>>(
      xb, wfcT, Yg, idx, offs, tmap, ntiles);
  gemm_proj<true><<<dim3(C_DIM / 128, MAXT), 256, 0, stream>>>(
      Yg, wprojT, Yout, offs, tmap, ntiles);

  // out[t] += w0*Yout[slot0] + w1*Yout[slot1]
  combine_kernel<<<NTOK, 256, 0, stream>>>(Yout, tok2slot, tok2w, out);
}